// Round 2
// baseline (1759.123 us; speedup 1.0000x reference)
//
#include <hip/hip_runtime.h>

// ---------------------------------------------------------------------------
// Nystrom attention, fp32, fused-softmax restructure (ws ~112 MB).
// B=4, N=4096, DIM=512, H=8, DH=64, M=256, l=16, 6 pinv iters, conv K=33.
// ---------------------------------------------------------------------------

constexpr size_t SQ = 8388608;   // 32*4096*64  (q/k/v per-tensor)
constexpr size_t SL = 524288;    // 32*256*64
constexpr size_t SA = 2097152;   // 32*256*256

constexpr size_t O_Q    = 0;                   // q -> later oh (in-place)
constexpr size_t O_K    = O_Q + SQ;            // k -> later Z0,Z1,Y1,Y2
constexpr size_t O_V    = O_K + SQ;
constexpr size_t O_QL   = O_V + SQ;
constexpr size_t O_KL   = O_QL + SL;
constexpr size_t O_A2   = O_KL + SL;           // attn2 (SA)
constexpr size_t O_T1   = O_A2 + SA;
constexpr size_t O_RS3  = O_T1 + SL;           // 32*256
constexpr size_t O_SCAL = O_RS3 + 8192;        // 16
constexpr size_t O_T2   = O_SCAL + 16;
constexpr size_t O_END  = O_T2 + SL;           // 29,368,336 floats ~112 MB

// ---------------------------------------------------------------------------
// 64x64 C-tile micro-kernel: 256 thr, 4x4/thread, 16 k-steps, LDS stride 68
// ---------------------------------------------------------------------------
__device__ __forceinline__ void mt16(const float* As, const float* Bs,
                                     int ty4, int tx4, float (&acc)[4][4]) {
#pragma unroll
    for (int kk = 0; kk < 16; ++kk) {
        float4 a4 = *(const float4*)(As + kk * 68 + ty4);
        float4 b4 = *(const float4*)(Bs + kk * 68 + tx4);
        float aa[4] = {a4.x, a4.y, a4.z, a4.w};
        float bb[4] = {b4.x, b4.y, b4.z, b4.w};
#pragma unroll
        for (int u = 0; u < 4; ++u)
#pragma unroll
            for (int w = 0; w < 4; ++w)
                acc[u][w] += aa[u] * bb[w];
    }
}

// ---------------------------------------------------------------------------
// batched GEMM. C[M,N] = A[M,K] @ op(B). EPI: 0 store, 1 C=alpha*acc+beta*A.
// DIVB: divide B row k by divv[z*K+k].
// ---------------------------------------------------------------------------
template <bool TRANSB, int EPI, bool DIVB>
__global__ __launch_bounds__(256) void gemm_bk(
    const float* __restrict__ A, int saA, int lda,
    const float* __restrict__ B, int sbB, int ldb,
    float* __restrict__ C, int scC, int ldc,
    int K, float alpha, float beta, const float* __restrict__ divv) {
    __shared__ float As[16 * 68];
    __shared__ float Bs[16 * 68];
    const int t  = threadIdx.x;
    const int z  = blockIdx.z;
    const int m0 = blockIdx.y * 64;
    const int n0 = blockIdx.x * 64;
    const float* Ab = A + (size_t)z * saA;
    const float* Bb = B + (size_t)z * sbB;
    float*       Cb = C + (size_t)z * scC;
    const int tx4 = (t & 15) * 4;
    const int ty4 = (t >> 4) * 4;
    const int ar  = t >> 2, ak = (t & 3) * 4;
    const int bkr = t >> 4, bc4 = (t & 15) * 4;
    float acc[4][4] = {};

    for (int kt = 0; kt < K; kt += 16) {
        float4 av = *(const float4*)(Ab + (size_t)(m0 + ar) * lda + kt + ak);
        float4 bv;
        if (TRANSB) {
            bv = *(const float4*)(Bb + (size_t)(n0 + ar) * ldb + kt + ak);
        } else {
            bv = *(const float4*)(Bb + (size_t)(kt + bkr) * ldb + n0 + bc4);
            if (DIVB) {
                float r = 1.0f / divv[z * K + kt + bkr];
                bv.x *= r; bv.y *= r; bv.z *= r; bv.w *= r;
            }
        }
        As[(ak + 0) * 68 + ar] = av.x;
        As[(ak + 1) * 68 + ar] = av.y;
        As[(ak + 2) * 68 + ar] = av.z;
        As[(ak + 3) * 68 + ar] = av.w;
        if (TRANSB) {
            Bs[(ak + 0) * 68 + ar] = bv.x;
            Bs[(ak + 1) * 68 + ar] = bv.y;
            Bs[(ak + 2) * 68 + ar] = bv.z;
            Bs[(ak + 3) * 68 + ar] = bv.w;
        } else {
            *(float4*)(Bs + bkr * 68 + bc4) = bv;
        }
        __syncthreads();
        mt16(As, Bs, ty4, tx4, acc);
        __syncthreads();
    }
#pragma unroll
    for (int u = 0; u < 4; ++u) {
        int row = m0 + ty4 + u;
        float4 o = make_float4(acc[u][0], acc[u][1], acc[u][2], acc[u][3]);
        size_t cidx = (size_t)row * ldc + n0 + tx4;
        if (EPI == 1) {
            float4 ae = *(const float4*)(Ab + (size_t)row * lda + n0 + tx4);
            o.x = alpha * o.x + beta * ae.x;
            o.y = alpha * o.y + beta * ae.y;
            o.z = alpha * o.z + beta * ae.z;
            o.w = alpha * o.w + beta * ae.w;
        }
        *(float4*)(Cb + cidx) = o;
    }
}

// ---------------------------------------------------------------------------
// qkv GEMM [16384,512]@[512,1536] with q(*0.125)/k/v head-layout scatter
// ---------------------------------------------------------------------------
__global__ __launch_bounds__(256) void gemm_qkv(
    const float* __restrict__ X, const float* __restrict__ W,
    float* __restrict__ qb, float* __restrict__ kb, float* __restrict__ vb) {
    __shared__ float As[16 * 68];
    __shared__ float Bs[16 * 68];
    const int t  = threadIdx.x;
    const int n0 = blockIdx.x * 64;
    const int m0 = blockIdx.y * 64;
    const int tx4 = (t & 15) * 4;
    const int ty4 = (t >> 4) * 4;
    const int ar = t >> 2, ak = (t & 3) * 4;
    const int bkr = t >> 4, bc4 = (t & 15) * 4;
    float acc[4][4] = {};
    for (int kt = 0; kt < 512; kt += 16) {
        float4 av = *(const float4*)(X + (size_t)(m0 + ar) * 512 + kt + ak);
        float4 bv = *(const float4*)(W + (size_t)(kt + bkr) * 1536 + n0 + bc4);
        As[(ak + 0) * 68 + ar] = av.x;
        As[(ak + 1) * 68 + ar] = av.y;
        As[(ak + 2) * 68 + ar] = av.z;
        As[(ak + 3) * 68 + ar] = av.w;
        *(float4*)(Bs + bkr * 68 + bc4) = bv;
        __syncthreads();
        mt16(As, Bs, ty4, tx4, acc);
        __syncthreads();
    }
    const int which = n0 >> 9;
    const int h     = (n0 & 511) >> 6;
    const float sc  = (which == 0) ? 0.125f : 1.0f;
    float* dst = (which == 0) ? qb : (which == 1 ? kb : vb);
#pragma unroll
    for (int u = 0; u < 4; ++u) {
        int row = m0 + ty4 + u;
        int b = row >> 12, n = row & 4095;
        float4 o = make_float4(acc[u][0] * sc, acc[u][1] * sc,
                               acc[u][2] * sc, acc[u][3] * sc);
        *(float4*)(dst + (size_t)(b * 8 + h) * 262144 + (size_t)n * 64 + tx4) = o;
    }
}

// ---------------------------------------------------------------------------
// F3: t1_raw += exp(qland@k^T)@v per chunk; rs3 += rowsums. split-K atomic.
// grid (8 chunkgroups, 4 mtiles, 32 bh)
// ---------------------------------------------------------------------------
__global__ __launch_bounds__(256) void fused_attn3v(
    const float* __restrict__ qland, const float* __restrict__ k,
    const float* __restrict__ v, float* __restrict__ t1,
    float* __restrict__ rs3) {
    __shared__ float Aq[64 * 68];
    __shared__ float Bk[64 * 68];
    __shared__ float Es[64 * 68];
    __shared__ float rsL[64];
    const int t = threadIdx.x;
    const int bz = blockIdx.z;
    const int m0 = blockIdx.y * 64;
    const int c0 = blockIdx.x * 8;
    const int tx4 = (t & 15) * 4;
    const int ty4 = (t >> 4) * 4;
    const int ar = t >> 2, ak = (t & 3) * 4;
    const float* qb = qland + (size_t)bz * 16384;
    const float* kb = k + (size_t)bz * 262144;
    const float* vb = v + (size_t)bz * 262144;
#pragma unroll
    for (int kt2 = 0; kt2 < 64; kt2 += 16) {
        float4 av = *(const float4*)(qb + (size_t)(m0 + ar) * 64 + kt2 + ak);
        Aq[(kt2 + ak + 0) * 68 + ar] = av.x;
        Aq[(kt2 + ak + 1) * 68 + ar] = av.y;
        Aq[(kt2 + ak + 2) * 68 + ar] = av.z;
        Aq[(kt2 + ak + 3) * 68 + ar] = av.w;
    }
    float acc_o[4][4] = {};
    float rsum[4] = {};
    if (t < 64) rsL[t] = 0.f;
    __syncthreads();

    for (int c = c0; c < c0 + 8; ++c) {
        const int tok0 = c * 64;
#pragma unroll
        for (int kt2 = 0; kt2 < 64; kt2 += 16) {
            float4 bv = *(const float4*)(kb + (size_t)(tok0 + ar) * 64 + kt2 + ak);
            Bk[(kt2 + ak + 0) * 68 + ar] = bv.x;
            Bk[(kt2 + ak + 1) * 68 + ar] = bv.y;
            Bk[(kt2 + ak + 2) * 68 + ar] = bv.z;
            Bk[(kt2 + ak + 3) * 68 + ar] = bv.w;
        }
        __syncthreads();
        float s[4][4] = {};
#pragma unroll
        for (int kt2 = 0; kt2 < 64; kt2 += 16)
            mt16(Aq + kt2 * 68, Bk + kt2 * 68, ty4, tx4, s);
        __syncthreads();                       // done reading Bk (k)
#pragma unroll
        for (int u = 0; u < 4; ++u)
#pragma unroll
            for (int w = 0; w < 4; ++w) {
                float e = __expf(s[u][w]);
                rsum[u] += e;
                Es[(tx4 + w) * 68 + ty4 + u] = e;   // [token][qrow]
            }
#pragma unroll
        for (int p = 0; p < 4; ++p) {
            int idx = p * 256 + t;
            int tok = idx >> 4, dh0 = (idx & 15) * 4;
            *(float4*)(Bk + tok * 68 + dh0) =
                *(const float4*)(vb + (size_t)(tok0 + tok) * 64 + dh0);
        }
        __syncthreads();                       // Es + v ready
#pragma unroll
        for (int kt2 = 0; kt2 < 64; kt2 += 16)
            mt16(Es + kt2 * 68, Bk + kt2 * 68, ty4, tx4, acc_o);
        __syncthreads();                       // before next chunk overwrite
    }
    float* t1b = t1 + (size_t)bz * 16384;
#pragma unroll
    for (int u = 0; u < 4; ++u) {
        atomicAdd(&rsL[ty4 + u], rsum[u]);
#pragma unroll
        for (int w = 0; w < 4; ++w)
            atomicAdd(t1b + (size_t)(m0 + ty4 + u) * 64 + tx4 + w, acc_o[u][w]);
    }
    __syncthreads();
    if (t < 64) atomicAdd(rs3 + bz * 256 + m0 + t, rsL[t]);
}

// ---------------------------------------------------------------------------
// F1: oh = softmax(q@kland^T)@t2 (normalized), oh aliases q (per-block safe).
// grid (64 mtiles, 32 bh)
// ---------------------------------------------------------------------------
__global__ __launch_bounds__(256) void fused_attn1t2(
    const float* __restrict__ q, const float* __restrict__ kland,
    const float* __restrict__ t2, float* __restrict__ oh) {
    __shared__ float Aq[64 * 68];
    __shared__ float Bl[64 * 68];
    __shared__ float Es[64 * 68];
    __shared__ float rsL[64];
    const int t = threadIdx.x;
    const int bz = blockIdx.y;
    const int m0 = blockIdx.x * 64;
    const int tx4 = (t & 15) * 4;
    const int ty4 = (t >> 4) * 4;
    const int ar = t >> 2, ak = (t & 3) * 4;
    const float* qb  = q + (size_t)bz * 262144;
    const float* klb = kland + (size_t)bz * 16384;
    const float* t2b = t2 + (size_t)bz * 16384;
#pragma unroll
    for (int kt2 = 0; kt2 < 64; kt2 += 16) {
        float4 av = *(const float4*)(qb + (size_t)(m0 + ar) * 64 + kt2 + ak);
        Aq[(kt2 + ak + 0) * 68 + ar] = av.x;
        Aq[(kt2 + ak + 1) * 68 + ar] = av.y;
        Aq[(kt2 + ak + 2) * 68 + ar] = av.z;
        Aq[(kt2 + ak + 3) * 68 + ar] = av.w;
    }
    float acc_o[4][4] = {};
    float rsum[4] = {};
    if (t < 64) rsL[t] = 0.f;
    __syncthreads();

    for (int lc = 0; lc < 4; ++lc) {
        const int l0 = lc * 64;
#pragma unroll
        for (int kt2 = 0; kt2 < 64; kt2 += 16) {
            float4 bv = *(const float4*)(klb + (size_t)(l0 + ar) * 64 + kt2 + ak);
            Bl[(kt2 + ak + 0) * 68 + ar] = bv.x;
            Bl[(kt2 + ak + 1) * 68 + ar] = bv.y;
            Bl[(kt2 + ak + 2) * 68 + ar] = bv.z;
            Bl[(kt2 + ak + 3) * 68 + ar] = bv.w;
        }
        __syncthreads();
        float s[4][4] = {};
#pragma unroll
        for (int kt2 = 0; kt2 < 64; kt2 += 16)
            mt16(Aq + kt2 * 68, Bl + kt2 * 68, ty4, tx4, s);
        __syncthreads();
#pragma unroll
        for (int u = 0; u < 4; ++u)
#pragma unroll
            for (int w = 0; w < 4; ++w) {
                float e = __expf(s[u][w]);
                rsum[u] += e;
                Es[(tx4 + w) * 68 + ty4 + u] = e;
            }
#pragma unroll
        for (int p = 0; p < 4; ++p) {
            int idx = p * 256 + t;
            int land = idx >> 4, dh0 = (idx & 15) * 4;
            *(float4*)(Bl + land * 68 + dh0) =
                *(const float4*)(t2b + (size_t)(l0 + land) * 64 + dh0);
        }
        __syncthreads();
#pragma unroll
        for (int kt2 = 0; kt2 < 64; kt2 += 16)
            mt16(Es + kt2 * 68, Bl + kt2 * 68, ty4, tx4, acc_o);
        __syncthreads();
    }
#pragma unroll
    for (int u = 0; u < 4; ++u) atomicAdd(&rsL[ty4 + u], rsum[u]);
    __syncthreads();
    float* ohb = oh + (size_t)bz * 262144;
#pragma unroll
    for (int u = 0; u < 4; ++u) {
        float rinv = 1.0f / rsL[ty4 + u];
        *(float4*)(ohb + (size_t)(m0 + ty4 + u) * 64 + tx4) =
            make_float4(acc_o[u][0] * rinv, acc_o[u][1] * rinv,
                        acc_o[u][2] * rinv, acc_o[u][3] * rinv);
    }
}

// ---------------------------------------------------------------------------
// final GEMM: out[b*n,512] = oh([b,h,n,d] gathered) @ w_out[512,512]
// ---------------------------------------------------------------------------
__global__ __launch_bounds__(256) void gemm_final(
    const float* __restrict__ OH, const float* __restrict__ W,
    float* __restrict__ out) {
    __shared__ float As[16 * 68];
    __shared__ float Bs[16 * 68];
    const int t  = threadIdx.x;
    const int n0 = blockIdx.x * 64;
    const int m0 = blockIdx.y * 64;
    const int tx4 = (t & 15) * 4;
    const int ty4 = (t >> 4) * 4;
    const int ar = t >> 2, ak = (t & 3) * 4;
    const int bkr = t >> 4, bc4 = (t & 15) * 4;
    float acc[4][4] = {};
    for (int kt = 0; kt < 512; kt += 16) {
        int r = m0 + ar, kc = kt + ak;
        int b = r >> 12, n = r & 4095;
        float4 av = *(const float4*)(OH + (size_t)(b * 8 + (kc >> 6)) * 262144
                                        + (size_t)n * 64 + (kc & 63));
        float4 bv = *(const float4*)(W + (size_t)(kt + bkr) * 512 + n0 + bc4);
        As[(ak + 0) * 68 + ar] = av.x;
        As[(ak + 1) * 68 + ar] = av.y;
        As[(ak + 2) * 68 + ar] = av.z;
        As[(ak + 3) * 68 + ar] = av.w;
        *(float4*)(Bs + bkr * 68 + bc4) = bv;
        __syncthreads();
        mt16(As, Bs, ty4, tx4, acc);
        __syncthreads();
    }
#pragma unroll
    for (int u = 0; u < 4; ++u) {
        int row = m0 + ty4 + u;
        *(float4*)(out + (size_t)row * 512 + n0 + tx4) =
            make_float4(acc[u][0], acc[u][1], acc[u][2], acc[u][3]);
    }
}

// ---------------------------------------------------------------------------
// small kernels
// ---------------------------------------------------------------------------
__global__ void zero_f(float* __restrict__ p, int n) {
    int i = blockIdx.x * 256 + threadIdx.x;
    if (i < n) p[i] = 0.f;
}

__global__ void landmark_mean(const float* __restrict__ src, float* __restrict__ dst) {
    int o = blockIdx.x * 256 + threadIdx.x;          // 524288 total
    int d = o & 63, m = (o >> 6) & 255, bh = o >> 14;
    const float* s = src + (size_t)bh * 262144 + (size_t)m * 1024 + d;
    float acc = 0.f;
#pragma unroll
    for (int j = 0; j < 16; ++j) acc += s[j * 64];
    dst[o] = acc * (1.0f / 16.0f);
}

__global__ void softmax_rows(float* __restrict__ a) {
    __shared__ float red[256];
    int row = blockIdx.x, t = threadIdx.x;
    float v = a[(size_t)row * 256 + t];
    red[t] = v;
    __syncthreads();
    for (int s = 128; s > 0; s >>= 1) {
        if (t < s) red[t] = fmaxf(red[t], red[t + s]);
        __syncthreads();
    }
    float mx = red[0];
    __syncthreads();
    float e = __expf(v - mx);
    red[t] = e;
    __syncthreads();
    for (int s = 128; s > 0; s >>= 1) {
        if (t < s) red[t] += red[t + s];
        __syncthreads();
    }
    a[(size_t)row * 256 + t] = e / red[0];
}

__global__ __launch_bounds__(256) void scalar_prep(const float* __restrict__ a,
                                                   float* __restrict__ scal) {
    __shared__ float red[256];
    int bh = blockIdx.x, t = threadIdx.x;
    const float* ab = a + (size_t)bh * 65536;
    float cs = 0.f;
    for (int i = 0; i < 256; ++i) cs += ab[i * 256 + t];
    red[t] = cs;
    __syncthreads();
    for (int s = 128; s > 0; s >>= 1) {
        if (t < s) red[t] = fmaxf(red[t], red[t + s]);
        __syncthreads();
    }
    float mcol = red[0];
    __syncthreads();
    float rs = 0.f;
    for (int j = 0; j < 256; ++j) rs += ab[t * 256 + j];
    red[t] = rs;
    __syncthreads();
    for (int s = 128; s > 0; s >>= 1) {
        if (t < s) red[t] = fmaxf(red[t], red[t + s]);
        __syncthreads();
    }
    if (t == 0) {
        atomicMax((unsigned int*)&scal[0], __float_as_uint(mcol));
        atomicMax((unsigned int*)&scal[1], __float_as_uint(red[0]));
    }
}

__global__ void zinit(const float* __restrict__ a, float* __restrict__ zz,
                      const float* __restrict__ scal) {
    int idx = blockIdx.x * 256 + threadIdx.x;        // 2,097,152 total
    int bh = idx >> 16, r = (idx >> 8) & 255, c = idx & 255;
    float denom = scal[0] * scal[1] + 1e-8f;
    zz[idx] = a[((size_t)bh << 16) + ((size_t)c << 8) + r] / denom;
}

__global__ __launch_bounds__(256) void conv_add(
    float* __restrict__ oh, const float* __restrict__ v,
    const float* __restrict__ wres) {
    int idx = blockIdx.x * 256 + threadIdx.x;        // 8,388,608 total
    int d = idx & 63, n = (idx >> 6) & 4095, bh = idx >> 18;
    int h = bh & 7;
    float acc = oh[idx];
    const float* vb = v + (size_t)bh * 262144 + d;
    const float* wb = wres + h * 33;
#pragma unroll
    for (int tt = 0; tt < 33; ++tt) {
        int j = n + tt - 16;
        if ((unsigned)j < 4096u) acc += vb[(size_t)j * 64] * wb[tt];
    }
    oh[idx] = acc;
}

// ---------------------------------------------------------------------------
extern "C" void kernel_launch(void* const* d_in, const int* in_sizes, int n_in,
                              void* d_out, int out_size, void* d_ws, size_t ws_size,
                              hipStream_t stream) {
    const float* x     = (const float*)d_in[0];
    const float* w_qkv = (const float*)d_in[1];
    const float* w_out = (const float*)d_in[2];
    const float* w_res = (const float*)d_in[3];
    float* out = (float*)d_out;
    float* ws  = (float*)d_ws;

    float* q     = ws + O_Q;     // becomes oh
    float* k     = ws + O_K;     // becomes Z0,Z1,Y1,Y2
    float* v     = ws + O_V;
    float* qland = ws + O_QL;
    float* kland = ws + O_KL;
    float* attn2 = ws + O_A2;
    float* t1    = ws + O_T1;
    float* rs3   = ws + O_RS3;
    float* scal  = ws + O_SCAL;
    float* t2    = ws + O_T2;

    // zero t1 + rs3 + scal (contiguous: 524288 + 8192 + 16)
    zero_f<<<2081, 256, 0, stream>>>(t1, 532496);

    // qkv projection + head scatter (+ q scale)
    gemm_qkv<<<dim3(24, 256), 256, 0, stream>>>(x, w_qkv, q, k, v);

    // landmarks
    landmark_mean<<<2048, 256, 0, stream>>>(q, qland);
    landmark_mean<<<2048, 256, 0, stream>>>(k, kland);

    // attn2 = softmax(q_land @ k_land^T)
    gemm_bk<true, 0, false><<<dim3(4, 4, 32), 256, 0, stream>>>(
        qland, 16384, 64, kland, 16384, 64, attn2, 65536, 256, 64, 0.f, 0.f,
        nullptr);
    softmax_rows<<<8192, 256, 0, stream>>>(attn2);

    // F3: t1_raw, rs3  (k dies after this)
    fused_attn3v<<<dim3(8, 4, 32), 256, 0, stream>>>(qland, k, v, t1, rs3);

    // pinv in k's slot
    float* Z0 = k;
    float* Z1 = k + SA;
    float* Y1 = k + 2 * SA;
    float* Y2 = k + 3 * SA;
    scalar_prep<<<32, 256, 0, stream>>>(attn2, scal);
    zinit<<<8192, 256, 0, stream>>>(attn2, Z0, scal);

    float* Zbuf[2] = {Z0, Z1};
    int cur = 0;
    for (int it = 0; it < 6; ++it) {
        float* zc = Zbuf[cur];
        float* xz = Zbuf[1 - cur];
        gemm_bk<false, 0, false><<<dim3(4, 4, 32), 256, 0, stream>>>(
            attn2, 65536, 256, zc, 65536, 256, xz, 65536, 256, 256, 0.f, 0.f,
            nullptr);
        gemm_bk<false, 1, false><<<dim3(4, 4, 32), 256, 0, stream>>>(
            xz, 65536, 256, xz, 65536, 256, Y1, 65536, 256, 256, -1.f, 7.f,
            nullptr);
        gemm_bk<false, 1, false><<<dim3(4, 4, 32), 256, 0, stream>>>(
            xz, 65536, 256, Y1, 65536, 256, Y2, 65536, 256, 256, -1.f, 15.f,
            nullptr);
        gemm_bk<false, 1, false><<<dim3(4, 4, 32), 256, 0, stream>>>(
            zc, 65536, 256, Y2, 65536, 256, xz, 65536, 256, 256, -0.25f, 3.25f,
            nullptr);
        cur = 1 - cur;
    }
    float* zfin = Zbuf[cur];

    // t2 = z @ (t1 / rs3)
    gemm_bk<false, 0, true><<<dim3(1, 4, 32), 256, 0, stream>>>(
        zfin, 65536, 256, t1, 16384, 64, t2, 16384, 64, 256, 0.f, 0.f, rs3);

    // F1: oh = softmax(q@kland^T)@t2  (writes over q, per-block safe)
    fused_attn1t2<<<dim3(64, 32), 256, 0, stream>>>(q, kland, t2, q);

    // oh += depthwise conv(v)
    conv_add<<<32768, 256, 0, stream>>>(q, v, w_res);

    // final projection
    gemm_final<<<dim3(8, 256), 256, 0, stream>>>(q, w_out, out);

    (void)in_sizes; (void)n_in; (void)out_size; (void)ws_size;
}

// Round 3
// 1297.383 us; speedup vs baseline: 1.3559x; 1.3559x over previous
//
#include <hip/hip_runtime.h>

// ---------------------------------------------------------------------------
// Nystrom attention: split-bf16 (hi/lo, 3xMFMA) GEMMs for qkv/pinv/final,
// fp32 fused flash kernels for attn1/attn3, fp32 small kernels.
// B=4, N=4096, DIM=512, H=8, DH=64, M=256, l=16, 6 pinv iters, conv K=33.
// ---------------------------------------------------------------------------

typedef __attribute__((ext_vector_type(8))) short bf16x8;
typedef __attribute__((ext_vector_type(4))) float f32x4;

constexpr size_t SQ = 8388608;   // 32*4096*64
constexpr size_t SL = 524288;    // 32*256*64
constexpr size_t SA = 2097152;   // 32*256*256
constexpr size_t SP = 1048576;   // one bf16 plane of SA (in float units)

// float-unit offsets
constexpr size_t O_Q    = 0;                   // q -> later oh (in-place)
constexpr size_t O_K    = O_Q + SQ;            // k -> later zA,zB (f32)
constexpr size_t O_V    = O_K + SQ;
constexpr size_t O_QL   = O_V + SQ;
constexpr size_t O_KL   = O_QL + SL;
constexpr size_t O_A2   = O_KL + SL;
constexpr size_t O_T1   = O_A2 + SA;
constexpr size_t O_RS3  = O_T1 + SL;
constexpr size_t O_SCAL = O_RS3 + 8192;
constexpr size_t O_T2   = O_SCAL + 16;
// bf16 plane region (each plane SP float-units = SA u16)
constexpr size_t O_ZT0  = O_T2 + SL;           // ZT0 h,l
constexpr size_t O_ZT1  = O_ZT0 + 2 * SP;
constexpr size_t O_XZT  = O_ZT1 + 2 * SP;
constexpr size_t O_Y1T  = O_XZT + 2 * SP;
constexpr size_t O_Y2T  = O_Y1T + 2 * SP;
constexpr size_t O_WQT  = O_Y2T + 2 * SP;      // 1536*512 u16 x2 = 786432 fl
constexpr size_t O_WOT  = O_WQT + 786432;      // 512*512 u16 x2 = 262144 fl
constexpr size_t O_END  = O_WOT + 262144;      // ~41.0M floats ~164 MB

// ---------------------------------------------------------------------------
__device__ __forceinline__ void split2(float x, unsigned short& h,
                                       unsigned short& l) {
    unsigned u  = __float_as_uint(x);
    unsigned hb = (u + 0x7FFFu + ((u >> 16) & 1u)) & 0xFFFF0000u;  // RNE hi
    h = (unsigned short)(hb >> 16);
    float d = x - __uint_as_float(hb);                              // exact
    l = (unsigned short)(__float_as_uint(d) >> 16);                 // trunc lo
}

__device__ __forceinline__ f32x4 mfma3(bf16x8 ah, bf16x8 al, bf16x8 bh,
                                       bf16x8 bl, f32x4 c) {
    c = __builtin_amdgcn_mfma_f32_16x16x32_bf16(ah, bh, c, 0, 0, 0);
    c = __builtin_amdgcn_mfma_f32_16x16x32_bf16(ah, bl, c, 0, 0, 0);
    c = __builtin_amdgcn_mfma_f32_16x16x32_bf16(al, bh, c, 0, 0, 0);
    return c;
}

#define LDS_DECL                                                     \
    __shared__ __align__(16) unsigned short Ah[128 * 40];            \
    __shared__ __align__(16) unsigned short Al[128 * 40];            \
    __shared__ __align__(16) unsigned short Bh[128 * 40];            \
    __shared__ __align__(16) unsigned short Bl[128 * 40];

// stage one float4 of A (4 k-consecutive fp32) into split LDS planes
__device__ __forceinline__ void stageA4(float4 av, unsigned short* Ahp,
                                        unsigned short* Alp, int row, int k4) {
    unsigned short h0, h1, h2, h3, l0, l1, l2, l3;
    split2(av.x, h0, l0); split2(av.y, h1, l1);
    split2(av.z, h2, l2); split2(av.w, h3, l3);
    uint2 ph, pl;
    ph.x = (unsigned)h0 | ((unsigned)h1 << 16);
    ph.y = (unsigned)h2 | ((unsigned)h3 << 16);
    pl.x = (unsigned)l0 | ((unsigned)l1 << 16);
    pl.y = (unsigned)l2 | ((unsigned)l3 << 16);
    *(uint2*)&Ahp[row * 40 + k4] = ph;
    *(uint2*)&Alp[row * 40 + k4] = pl;
}

// ---------------------------------------------------------------------------
// pinv-family MFMA GEMM: C = alpha*(A@B) + beta*A_elem, batched.
// A fp32 (split in-register); B given as transposed bf16 planes BT[n][k].
// Optionally writes C fp32 and/or C^T bf16 planes.
// grid (N/128, M/128, batch), block 256.
// ---------------------------------------------------------------------------
template <int EPI, bool WF32, bool WT>
__global__ __launch_bounds__(256) void mfma_gemm(
    const float* __restrict__ A, int lda, long saA,
    const unsigned short* __restrict__ BTh,
    const unsigned short* __restrict__ BTl, int ldbt, long sbT,
    float* __restrict__ C, int ldc, long scC,
    unsigned short* __restrict__ CTh, unsigned short* __restrict__ CTl,
    int ldct, long sct, int K, float alpha, float beta) {
    LDS_DECL
    const int t = threadIdx.x;
    const int wave = t >> 6, lane = t & 63;
    const int lm = lane & 15, lq = lane >> 4;
    const int z = blockIdx.z;
    const int m0 = blockIdx.y * 128, n0 = blockIdx.x * 128;
    const float* Ab = A + (size_t)z * saA;
    const unsigned short* BhB = BTh + (size_t)z * sbT;
    const unsigned short* BlB = BTl + (size_t)z * sbT;
    const int mb = (wave >> 1) * 64, nb = (wave & 1) * 64;

    f32x4 acc[4][4];
#pragma unroll
    for (int i = 0; i < 4; ++i)
#pragma unroll
        for (int j = 0; j < 4; ++j) acc[i][j] = (f32x4){0.f, 0.f, 0.f, 0.f};

    for (int kt = 0; kt < K; kt += 32) {
#pragma unroll
        for (int r = 0; r < 4; ++r) {
            int id = t + r * 256, row = id >> 3, k4 = (id & 7) * 4;
            float4 av = *(const float4*)(Ab + (size_t)(m0 + row) * lda + kt + k4);
            stageA4(av, Ah, Al, row, k4);
        }
#pragma unroll
        for (int r = 0; r < 2; ++r) {
            int id = t + r * 256, row = id >> 2, ko = (id & 3) * 8;
            *(uint4*)&Bh[row * 40 + ko] =
                *(const uint4*)(BhB + (size_t)(n0 + row) * ldbt + kt + ko);
            *(uint4*)&Bl[row * 40 + ko] =
                *(const uint4*)(BlB + (size_t)(n0 + row) * ldbt + kt + ko);
        }
        __syncthreads();
        bf16x8 ah[4], al[4], bh[4], bl[4];
#pragma unroll
        for (int i = 0; i < 4; ++i) {
            ah[i] = *(const bf16x8*)&Ah[(mb + i * 16 + lm) * 40 + lq * 8];
            al[i] = *(const bf16x8*)&Al[(mb + i * 16 + lm) * 40 + lq * 8];
        }
#pragma unroll
        for (int j = 0; j < 4; ++j) {
            bh[j] = *(const bf16x8*)&Bh[(nb + j * 16 + lm) * 40 + lq * 8];
            bl[j] = *(const bf16x8*)&Bl[(nb + j * 16 + lm) * 40 + lq * 8];
        }
#pragma unroll
        for (int i = 0; i < 4; ++i)
#pragma unroll
            for (int j = 0; j < 4; ++j)
                acc[i][j] = mfma3(ah[i], al[i], bh[j], bl[j], acc[i][j]);
        __syncthreads();
    }

    float* Cb = C + (size_t)z * scC;
    unsigned short* CThB = CTh + (size_t)z * sct;
    unsigned short* CTlB = CTl + (size_t)z * sct;
#pragma unroll
    for (int i = 0; i < 4; ++i)
#pragma unroll
        for (int j = 0; j < 4; ++j) {
            int r0 = m0 + mb + i * 16 + lq * 4;
            int c  = n0 + nb + j * 16 + lm;
            float vals[4] = {acc[i][j][0], acc[i][j][1], acc[i][j][2],
                             acc[i][j][3]};
            if (EPI == 1) {
#pragma unroll
                for (int e = 0; e < 4; ++e)
                    vals[e] = alpha * vals[e] +
                              beta * Ab[(size_t)(r0 + e) * lda + c];
            }
            if (WF32) {
#pragma unroll
                for (int e = 0; e < 4; ++e)
                    Cb[(size_t)(r0 + e) * ldc + c] = vals[e];
            }
            if (WT) {
                unsigned short hh[4], ll[4];
#pragma unroll
                for (int e = 0; e < 4; ++e) split2(vals[e], hh[e], ll[e]);
                uint2 ph, pl;
                ph.x = (unsigned)hh[0] | ((unsigned)hh[1] << 16);
                ph.y = (unsigned)hh[2] | ((unsigned)hh[3] << 16);
                pl.x = (unsigned)ll[0] | ((unsigned)ll[1] << 16);
                pl.y = (unsigned)ll[2] | ((unsigned)ll[3] << 16);
                *(uint2*)&CThB[(size_t)c * ldct + r0] = ph;
                *(uint2*)&CTlB[(size_t)c * ldct + r0] = pl;
            }
        }
}

// ---------------------------------------------------------------------------
// qkv MFMA GEMM: x[16384,512] @ w_qkv (planes, transposed), scatter epilogue.
// grid (12, 128).
// ---------------------------------------------------------------------------
__global__ __launch_bounds__(256) void mfma_qkv(
    const float* __restrict__ X, const unsigned short* __restrict__ WTh,
    const unsigned short* __restrict__ WTl, float* __restrict__ qb,
    float* __restrict__ kb, float* __restrict__ vb) {
    LDS_DECL
    const int t = threadIdx.x;
    const int wave = t >> 6, lane = t & 63;
    const int lm = lane & 15, lq = lane >> 4;
    const int m0 = blockIdx.y * 128, n0 = blockIdx.x * 128;
    const int mb = (wave >> 1) * 64, nb = (wave & 1) * 64;
    f32x4 acc[4][4];
#pragma unroll
    for (int i = 0; i < 4; ++i)
#pragma unroll
        for (int j = 0; j < 4; ++j) acc[i][j] = (f32x4){0.f, 0.f, 0.f, 0.f};

    for (int kt = 0; kt < 512; kt += 32) {
#pragma unroll
        for (int r = 0; r < 4; ++r) {
            int id = t + r * 256, row = id >> 3, k4 = (id & 7) * 4;
            float4 av = *(const float4*)(X + (size_t)(m0 + row) * 512 + kt + k4);
            stageA4(av, Ah, Al, row, k4);
        }
#pragma unroll
        for (int r = 0; r < 2; ++r) {
            int id = t + r * 256, row = id >> 2, ko = (id & 3) * 8;
            *(uint4*)&Bh[row * 40 + ko] =
                *(const uint4*)(WTh + (size_t)(n0 + row) * 512 + kt + ko);
            *(uint4*)&Bl[row * 40 + ko] =
                *(const uint4*)(WTl + (size_t)(n0 + row) * 512 + kt + ko);
        }
        __syncthreads();
        bf16x8 ah[4], al[4], bh[4], bl[4];
#pragma unroll
        for (int i = 0; i < 4; ++i) {
            ah[i] = *(const bf16x8*)&Ah[(mb + i * 16 + lm) * 40 + lq * 8];
            al[i] = *(const bf16x8*)&Al[(mb + i * 16 + lm) * 40 + lq * 8];
        }
#pragma unroll
        for (int j = 0; j < 4; ++j) {
            bh[j] = *(const bf16x8*)&Bh[(nb + j * 16 + lm) * 40 + lq * 8];
            bl[j] = *(const bf16x8*)&Bl[(nb + j * 16 + lm) * 40 + lq * 8];
        }
#pragma unroll
        for (int i = 0; i < 4; ++i)
#pragma unroll
            for (int j = 0; j < 4; ++j)
                acc[i][j] = mfma3(ah[i], al[i], bh[j], bl[j], acc[i][j]);
        __syncthreads();
    }
#pragma unroll
    for (int i = 0; i < 4; ++i)
#pragma unroll
        for (int j = 0; j < 4; ++j) {
            int r0 = m0 + mb + i * 16 + lq * 4;
            int c  = n0 + nb + j * 16 + lm;
            int which = c >> 9, h = (c >> 6) & 7, d = c & 63;
            float sc = (which == 0) ? 0.125f : 1.0f;
            float* dst = (which == 0) ? qb : (which == 1 ? kb : vb);
#pragma unroll
            for (int e = 0; e < 4; ++e) {
                int r = r0 + e, b = r >> 12, n = r & 4095;
                dst[(size_t)(b * 8 + h) * 262144 + (size_t)n * 64 + d] =
                    acc[i][j][e] * sc;
            }
        }
}

// ---------------------------------------------------------------------------
// final MFMA GEMM: out[16384,512] = oh(gathered [b,h,n,d]) @ w_out planes.
// grid (4, 128).
// ---------------------------------------------------------------------------
__global__ __launch_bounds__(256) void mfma_final(
    const float* __restrict__ OH, const unsigned short* __restrict__ WTh,
    const unsigned short* __restrict__ WTl, float* __restrict__ out) {
    LDS_DECL
    const int t = threadIdx.x;
    const int wave = t >> 6, lane = t & 63;
    const int lm = lane & 15, lq = lane >> 4;
    const int m0 = blockIdx.y * 128, n0 = blockIdx.x * 128;
    const int mb = (wave >> 1) * 64, nb = (wave & 1) * 64;
    f32x4 acc[4][4];
#pragma unroll
    for (int i = 0; i < 4; ++i)
#pragma unroll
        for (int j = 0; j < 4; ++j) acc[i][j] = (f32x4){0.f, 0.f, 0.f, 0.f};

    for (int kt = 0; kt < 512; kt += 32) {
#pragma unroll
        for (int r = 0; r < 4; ++r) {
            int id = t + r * 256, row = id >> 3, k4 = kt + (id & 7) * 4;
            int gr = m0 + row, b = gr >> 12, n = gr & 4095;
            int h = k4 >> 6, d = k4 & 63;
            float4 av = *(const float4*)(OH + (size_t)(b * 8 + h) * 262144 +
                                         (size_t)n * 64 + d);
            stageA4(av, Ah, Al, row, (id & 7) * 4);
        }
#pragma unroll
        for (int r = 0; r < 2; ++r) {
            int id = t + r * 256, row = id >> 2, ko = (id & 3) * 8;
            *(uint4*)&Bh[row * 40 + ko] =
                *(const uint4*)(WTh + (size_t)(n0 + row) * 512 + kt + ko);
            *(uint4*)&Bl[row * 40 + ko] =
                *(const uint4*)(WTl + (size_t)(n0 + row) * 512 + kt + ko);
        }
        __syncthreads();
        bf16x8 ah[4], al[4], bh[4], bl[4];
#pragma unroll
        for (int i = 0; i < 4; ++i) {
            ah[i] = *(const bf16x8*)&Ah[(mb + i * 16 + lm) * 40 + lq * 8];
            al[i] = *(const bf16x8*)&Al[(mb + i * 16 + lm) * 40 + lq * 8];
        }
#pragma unroll
        for (int j = 0; j < 4; ++j) {
            bh[j] = *(const bf16x8*)&Bh[(nb + j * 16 + lm) * 40 + lq * 8];
            bl[j] = *(const bf16x8*)&Bl[(nb + j * 16 + lm) * 40 + lq * 8];
        }
#pragma unroll
        for (int i = 0; i < 4; ++i)
#pragma unroll
            for (int j = 0; j < 4; ++j)
                acc[i][j] = mfma3(ah[i], al[i], bh[j], bl[j], acc[i][j]);
        __syncthreads();
    }
#pragma unroll
    for (int i = 0; i < 4; ++i)
#pragma unroll
        for (int j = 0; j < 4; ++j) {
            int r0 = m0 + mb + i * 16 + lq * 4;
            int c  = n0 + nb + j * 16 + lm;
#pragma unroll
            for (int e = 0; e < 4; ++e)
                out[(size_t)(r0 + e) * 512 + c] = acc[i][j][e];
        }
}

// ---------------------------------------------------------------------------
// weight transpose+split: W[K=512][N] -> planes T[N][512]
// ---------------------------------------------------------------------------
__global__ void wtrans(const float* __restrict__ W, int N,
                       unsigned short* __restrict__ Th,
                       unsigned short* __restrict__ Tl) {
    int idx = blockIdx.x * 256 + threadIdx.x;   // over N*512
    int n = idx >> 9, kk = idx & 511;
    float x = W[(size_t)kk * N + n];
    unsigned short h, l;
    split2(x, h, l);
    Th[idx] = h;
    Tl[idx] = l;
}

// ---------------------------------------------------------------------------
// fp32 64x64 micro-kernel + gemm_bk (attn2 + t2 only)
// ---------------------------------------------------------------------------
__device__ __forceinline__ void mt16(const float* As, const float* Bs,
                                     int ty4, int tx4, float (&acc)[4][4]) {
#pragma unroll
    for (int kk = 0; kk < 16; ++kk) {
        float4 a4 = *(const float4*)(As + kk * 68 + ty4);
        float4 b4 = *(const float4*)(Bs + kk * 68 + tx4);
        float aa[4] = {a4.x, a4.y, a4.z, a4.w};
        float bb[4] = {b4.x, b4.y, b4.z, b4.w};
#pragma unroll
        for (int u = 0; u < 4; ++u)
#pragma unroll
            for (int w = 0; w < 4; ++w)
                acc[u][w] += aa[u] * bb[w];
    }
}

template <bool TRANSB, bool DIVB>
__global__ __launch_bounds__(256) void gemm_bk(
    const float* __restrict__ A, int saA, int lda,
    const float* __restrict__ B, int sbB, int ldb,
    float* __restrict__ C, int scC, int ldc,
    int K, const float* __restrict__ divv) {
    __shared__ float As[16 * 68];
    __shared__ float Bs[16 * 68];
    const int t  = threadIdx.x;
    const int z  = blockIdx.z;
    const int m0 = blockIdx.y * 64;
    const int n0 = blockIdx.x * 64;
    const float* Ab = A + (size_t)z * saA;
    const float* Bb = B + (size_t)z * sbB;
    float*       Cb = C + (size_t)z * scC;
    const int tx4 = (t & 15) * 4;
    const int ty4 = (t >> 4) * 4;
    const int ar  = t >> 2, ak = (t & 3) * 4;
    const int bkr = t >> 4, bc4 = (t & 15) * 4;
    float acc[4][4] = {};
    for (int kt = 0; kt < K; kt += 16) {
        float4 av = *(const float4*)(Ab + (size_t)(m0 + ar) * lda + kt + ak);
        float4 bv;
        if (TRANSB) {
            bv = *(const float4*)(Bb + (size_t)(n0 + ar) * ldb + kt + ak);
        } else {
            bv = *(const float4*)(Bb + (size_t)(kt + bkr) * ldb + n0 + bc4);
            if (DIVB) {
                float r = 1.0f / divv[z * K + kt + bkr];
                bv.x *= r; bv.y *= r; bv.z *= r; bv.w *= r;
            }
        }
        As[(ak + 0) * 68 + ar] = av.x;
        As[(ak + 1) * 68 + ar] = av.y;
        As[(ak + 2) * 68 + ar] = av.z;
        As[(ak + 3) * 68 + ar] = av.w;
        if (TRANSB) {
            Bs[(ak + 0) * 68 + ar] = bv.x;
            Bs[(ak + 1) * 68 + ar] = bv.y;
            Bs[(ak + 2) * 68 + ar] = bv.z;
            Bs[(ak + 3) * 68 + ar] = bv.w;
        } else {
            *(float4*)(Bs + bkr * 68 + bc4) = bv;
        }
        __syncthreads();
        mt16(As, Bs, ty4, tx4, acc);
        __syncthreads();
    }
#pragma unroll
    for (int u = 0; u < 4; ++u) {
        int row = m0 + ty4 + u;
        *(float4*)(Cb + (size_t)row * ldc + n0 + tx4) =
            make_float4(acc[u][0], acc[u][1], acc[u][2], acc[u][3]);
    }
}

// ---------------------------------------------------------------------------
// fused flash kernels (fp32, unchanged from round 2)
// ---------------------------------------------------------------------------
__global__ __launch_bounds__(256) void fused_attn3v(
    const float* __restrict__ qland, const float* __restrict__ k,
    const float* __restrict__ v, float* __restrict__ t1,
    float* __restrict__ rs3) {
    __shared__ float Aq[64 * 68];
    __shared__ float Bk[64 * 68];
    __shared__ float Es[64 * 68];
    __shared__ float rsL[64];
    const int t = threadIdx.x;
    const int bz = blockIdx.z;
    const int m0 = blockIdx.y * 64;
    const int c0 = blockIdx.x * 8;
    const int tx4 = (t & 15) * 4;
    const int ty4 = (t >> 4) * 4;
    const int ar = t >> 2, ak = (t & 3) * 4;
    const float* qb = qland + (size_t)bz * 16384;
    const float* kb = k + (size_t)bz * 262144;
    const float* vb = v + (size_t)bz * 262144;
#pragma unroll
    for (int kt2 = 0; kt2 < 64; kt2 += 16) {
        float4 av = *(const float4*)(qb + (size_t)(m0 + ar) * 64 + kt2 + ak);
        Aq[(kt2 + ak + 0) * 68 + ar] = av.x;
        Aq[(kt2 + ak + 1) * 68 + ar] = av.y;
        Aq[(kt2 + ak + 2) * 68 + ar] = av.z;
        Aq[(kt2 + ak + 3) * 68 + ar] = av.w;
    }
    float acc_o[4][4] = {};
    float rsum[4] = {};
    if (t < 64) rsL[t] = 0.f;
    __syncthreads();
    for (int c = c0; c < c0 + 8; ++c) {
        const int tok0 = c * 64;
#pragma unroll
        for (int kt2 = 0; kt2 < 64; kt2 += 16) {
            float4 bv = *(const float4*)(kb + (size_t)(tok0 + ar) * 64 + kt2 + ak);
            Bk[(kt2 + ak + 0) * 68 + ar] = bv.x;
            Bk[(kt2 + ak + 1) * 68 + ar] = bv.y;
            Bk[(kt2 + ak + 2) * 68 + ar] = bv.z;
            Bk[(kt2 + ak + 3) * 68 + ar] = bv.w;
        }
        __syncthreads();
        float s[4][4] = {};
#pragma unroll
        for (int kt2 = 0; kt2 < 64; kt2 += 16)
            mt16(Aq + kt2 * 68, Bk + kt2 * 68, ty4, tx4, s);
        __syncthreads();
#pragma unroll
        for (int u = 0; u < 4; ++u)
#pragma unroll
            for (int w = 0; w < 4; ++w) {
                float e = __expf(s[u][w]);
                rsum[u] += e;
                Es[(tx4 + w) * 68 + ty4 + u] = e;
            }
#pragma unroll
        for (int p = 0; p < 4; ++p) {
            int idx = p * 256 + t;
            int tok = idx >> 4, dh0 = (idx & 15) * 4;
            *(float4*)(Bk + tok * 68 + dh0) =
                *(const float4*)(vb + (size_t)(tok0 + tok) * 64 + dh0);
        }
        __syncthreads();
#pragma unroll
        for (int kt2 = 0; kt2 < 64; kt2 += 16)
            mt16(Es + kt2 * 68, Bk + kt2 * 68, ty4, tx4, acc_o);
        __syncthreads();
    }
    float* t1b = t1 + (size_t)bz * 16384;
#pragma unroll
    for (int u = 0; u < 4; ++u) {
        atomicAdd(&rsL[ty4 + u], rsum[u]);
#pragma unroll
        for (int w = 0; w < 4; ++w)
            atomicAdd(t1b + (size_t)(m0 + ty4 + u) * 64 + tx4 + w, acc_o[u][w]);
    }
    __syncthreads();
    if (t < 64) atomicAdd(rs3 + bz * 256 + m0 + t, rsL[t]);
}

__global__ __launch_bounds__(256) void fused_attn1t2(
    const float* __restrict__ q, const float* __restrict__ kland,
    const float* __restrict__ t2, float* __restrict__ oh) {
    __shared__ float Aq[64 * 68];
    __shared__ float Bl[64 * 68];
    __shared__ float Es[64 * 68];
    __shared__ float rsL[64];
    const int t = threadIdx.x;
    const int bz = blockIdx.y;
    const int m0 = blockIdx.x * 64;
    const int tx4 = (t & 15) * 4;
    const int ty4 = (t >> 4) * 4;
    const int ar = t >> 2, ak = (t & 3) * 4;
    const float* qb  = q + (size_t)bz * 262144;
    const float* klb = kland + (size_t)bz * 16384;
    const float* t2b = t2 + (size_t)bz * 16384;
#pragma unroll
    for (int kt2 = 0; kt2 < 64; kt2 += 16) {
        float4 av = *(const float4*)(qb + (size_t)(m0 + ar) * 64 + kt2 + ak);
        Aq[(kt2 + ak + 0) * 68 + ar] = av.x;
        Aq[(kt2 + ak + 1) * 68 + ar] = av.y;
        Aq[(kt2 + ak + 2) * 68 + ar] = av.z;
        Aq[(kt2 + ak + 3) * 68 + ar] = av.w;
    }
    float acc_o[4][4] = {};
    float rsum[4] = {};
    if (t < 64) rsL[t] = 0.f;
    __syncthreads();
    for (int lc = 0; lc < 4; ++lc) {
        const int l0 = lc * 64;
#pragma unroll
        for (int kt2 = 0; kt2 < 64; kt2 += 16) {
            float4 bv = *(const float4*)(klb + (size_t)(l0 + ar) * 64 + kt2 + ak);
            Bl[(kt2 + ak + 0) * 68 + ar] = bv.x;
            Bl[(kt2 + ak + 1) * 68 + ar] = bv.y;
            Bl[(kt2 + ak + 2) * 68 + ar] = bv.z;
            Bl[(kt2 + ak + 3) * 68 + ar] = bv.w;
        }
        __syncthreads();
        float s[4][4] = {};
#pragma unroll
        for (int kt2 = 0; kt2 < 64; kt2 += 16)
            mt16(Aq + kt2 * 68, Bl + kt2 * 68, ty4, tx4, s);
        __syncthreads();
#pragma unroll
        for (int u = 0; u < 4; ++u)
#pragma unroll
            for (int w = 0; w < 4; ++w) {
                float e = __expf(s[u][w]);
                rsum[u] += e;
                Es[(tx4 + w) * 68 + ty4 + u] = e;
            }
#pragma unroll
        for (int p = 0; p < 4; ++p) {
            int idx = p * 256 + t;
            int land = idx >> 4, dh0 = (idx & 15) * 4;
            *(float4*)(Bl + land * 68 + dh0) =
                *(const float4*)(t2b + (size_t)(l0 + land) * 64 + dh0);
        }
        __syncthreads();
#pragma unroll
        for (int kt2 = 0; kt2 < 64; kt2 += 16)
            mt16(Es + kt2 * 68, Bl + kt2 * 68, ty4, tx4, acc_o);
        __syncthreads();
    }
#pragma unroll
    for (int u = 0; u < 4; ++u) atomicAdd(&rsL[ty4 + u], rsum[u]);
    __syncthreads();
    float* ohb = oh + (size_t)bz * 262144;
#pragma unroll
    for (int u = 0; u < 4; ++u) {
        float rinv = 1.0f / rsL[ty4 + u];
        *(float4*)(ohb + (size_t)(m0 + ty4 + u) * 64 + tx4) =
            make_float4(acc_o[u][0] * rinv, acc_o[u][1] * rinv,
                        acc_o[u][2] * rinv, acc_o[u][3] * rinv);
    }
}

// ---------------------------------------------------------------------------
// small kernels
// ---------------------------------------------------------------------------
__global__ void zero_f(float* __restrict__ p, int n) {
    int i = blockIdx.x * 256 + threadIdx.x;
    if (i < n) p[i] = 0.f;
}

__global__ void landmark_mean(const float* __restrict__ src,
                              float* __restrict__ dst) {
    int o = blockIdx.x * 256 + threadIdx.x;
    int d = o & 63, m = (o >> 6) & 255, bh = o >> 14;
    const float* s = src + (size_t)bh * 262144 + (size_t)m * 1024 + d;
    float acc = 0.f;
#pragma unroll
    for (int j = 0; j < 16; ++j) acc += s[j * 64];
    dst[o] = acc * (1.0f / 16.0f);
}

__global__ void softmax_rows(float* __restrict__ a) {
    __shared__ float red[256];
    int row = blockIdx.x, t = threadIdx.x;
    float v = a[(size_t)row * 256 + t];
    red[t] = v;
    __syncthreads();
    for (int s = 128; s > 0; s >>= 1) {
        if (t < s) red[t] = fmaxf(red[t], red[t + s]);
        __syncthreads();
    }
    float mx = red[0];
    __syncthreads();
    float e = __expf(v - mx);
    red[t] = e;
    __syncthreads();
    for (int s = 128; s > 0; s >>= 1) {
        if (t < s) red[t] += red[t + s];
        __syncthreads();
    }
    a[(size_t)row * 256 + t] = e / red[0];
}

__global__ __launch_bounds__(256) void scalar_prep(const float* __restrict__ a,
                                                   float* __restrict__ scal) {
    __shared__ float red[256];
    int bh = blockIdx.x, t = threadIdx.x;
    const float* ab = a + (size_t)bh * 65536;
    float cs = 0.f;
    for (int i = 0; i < 256; ++i) cs += ab[i * 256 + t];
    red[t] = cs;
    __syncthreads();
    for (int s = 128; s > 0; s >>= 1) {
        if (t < s) red[t] = fmaxf(red[t], red[t + s]);
        __syncthreads();
    }
    float mcol = red[0];
    __syncthreads();
    float rs = 0.f;
    for (int j = 0; j < 256; ++j) rs += ab[t * 256 + j];
    red[t] = rs;
    __syncthreads();
    for (int s = 128; s > 0; s >>= 1) {
        if (t < s) red[t] = fmaxf(red[t], red[t + s]);
        __syncthreads();
    }
    if (t == 0) {
        atomicMax((unsigned int*)&scal[0], __float_as_uint(mcol));
        atomicMax((unsigned int*)&scal[1], __float_as_uint(red[0]));
    }
}

// z = attn2^T/denom (f32) and zT planes (= attn2/denom, natural order)
__global__ void zinit(const float* __restrict__ a, float* __restrict__ zz,
                      unsigned short* __restrict__ zTh,
                      unsigned short* __restrict__ zTl,
                      const float* __restrict__ scal) {
    int idx = blockIdx.x * 256 + threadIdx.x;   // enumerates attn2 elements
    int bh = idx >> 16, r = (idx >> 8) & 255, c = idx & 255;
    float denom = scal[0] * scal[1] + 1e-8f;
    float v = a[idx] / denom;
    zz[((size_t)bh << 16) + ((size_t)c << 8) + r] = v;
    unsigned short h, l;
    split2(v, h, l);
    zTh[idx] = h;
    zTl[idx] = l;
}

__global__ __launch_bounds__(256) void conv_add(
    float* __restrict__ oh, const float* __restrict__ v,
    const float* __restrict__ wres) {
    int idx = blockIdx.x * 256 + threadIdx.x;
    int d = idx & 63, n = (idx >> 6) & 4095, bh = idx >> 18;
    int h = bh & 7;
    float acc = oh[idx];
    const float* vb = v + (size_t)bh * 262144 + d;
    const float* wb = wres + h * 33;
#pragma unroll
    for (int tt = 0; tt < 33; ++tt) {
        int j = n + tt - 16;
        if ((unsigned)j < 4096u) acc += vb[(size_t)j * 64] * wb[tt];
    }
    oh[idx] = acc;
}

// ---------------------------------------------------------------------------
extern "C" void kernel_launch(void* const* d_in, const int* in_sizes, int n_in,
                              void* d_out, int out_size, void* d_ws, size_t ws_size,
                              hipStream_t stream) {
    const float* x     = (const float*)d_in[0];
    const float* w_qkv = (const float*)d_in[1];
    const float* w_out = (const float*)d_in[2];
    const float* w_res = (const float*)d_in[3];
    float* out = (float*)d_out;
    float* ws  = (float*)d_ws;

    float* q     = ws + O_Q;
    float* k     = ws + O_K;
    float* v     = ws + O_V;
    float* qland = ws + O_QL;
    float* kland = ws + O_KL;
    float* attn2 = ws + O_A2;
    float* t1    = ws + O_T1;
    float* rs3   = ws + O_RS3;
    float* scal  = ws + O_SCAL;
    float* t2    = ws + O_T2;
    float* zA    = k;            // pinv f32 iterates (k dead after F3)
    float* zB    = k + SA;

    unsigned short* ZT0h = (unsigned short*)(ws + O_ZT0);
    unsigned short* ZT0l = (unsigned short*)(ws + O_ZT0 + SP);
    unsigned short* ZT1h = (unsigned short*)(ws + O_ZT1);
    unsigned short* ZT1l = (unsigned short*)(ws + O_ZT1 + SP);
    unsigned short* XZTh = (unsigned short*)(ws + O_XZT);
    unsigned short* XZTl = (unsigned short*)(ws + O_XZT + SP);
    unsigned short* Y1Th = (unsigned short*)(ws + O_Y1T);
    unsigned short* Y1Tl = (unsigned short*)(ws + O_Y1T + SP);
    unsigned short* Y2Th = (unsigned short*)(ws + O_Y2T);
    unsigned short* Y2Tl = (unsigned short*)(ws + O_Y2T + SP);
    unsigned short* WQTh = (unsigned short*)(ws + O_WQT);
    unsigned short* WQTl = (unsigned short*)(ws + O_WQT + 393216);
    unsigned short* WOTh = (unsigned short*)(ws + O_WOT);
    unsigned short* WOTl = (unsigned short*)(ws + O_WOT + 131072);

    zero_f<<<2081, 256, 0, stream>>>(t1, 532496);   // t1+rs3+scal
    wtrans<<<3072, 256, 0, stream>>>(w_qkv, 1536, WQTh, WQTl);
    wtrans<<<1024, 256, 0, stream>>>(w_out, 512, WOTh, WOTl);

    mfma_qkv<<<dim3(12, 128), 256, 0, stream>>>(x, WQTh, WQTl, q, k, v);

    landmark_mean<<<2048, 256, 0, stream>>>(q, qland);
    landmark_mean<<<2048, 256, 0, stream>>>(k, kland);

    gemm_bk<true, false><<<dim3(4, 4, 32), 256, 0, stream>>>(
        qland, 16384, 64, kland, 16384, 64, attn2, 65536, 256, 64, nullptr);
    softmax_rows<<<8192, 256, 0, stream>>>(attn2);
    scalar_prep<<<32, 256, 0, stream>>>(attn2, scal);

    // F3 before pinv (k dies here)
    fused_attn3v<<<dim3(8, 4, 32), 256, 0, stream>>>(qland, k, v, t1, rs3);

    zinit<<<8192, 256, 0, stream>>>(attn2, zA, ZT0h, ZT0l, scal);

    unsigned short* ZTh[2] = {ZT0h, ZT1h};
    unsigned short* ZTl[2] = {ZT0l, ZT1l};
    float* Zf[2] = {zA, zB};
    int cur = 0;
    const dim3 pg(2, 2, 32);
    for (int it = 0; it < 6; ++it) {
        float* zc  = Zf[cur];
        float* xzf = Zf[1 - cur];
        // st1: xz = attn2 @ z
        mfma_gemm<0, true, true><<<pg, 256, 0, stream>>>(
            attn2, 256, 65536, ZTh[cur], ZTl[cur], 256, 65536,
            xzf, 256, 65536, XZTh, XZTl, 256, 65536, 256, 0.f, 0.f);
        // st2: Y1 = -xz@xz + 7 xz   (planes only)
        mfma_gemm<1, false, true><<<pg, 256, 0, stream>>>(
            xzf, 256, 65536, XZTh, XZTl, 256, 65536,
            nullptr, 256, 65536, Y1Th, Y1Tl, 256, 65536, 256, -1.f, 7.f);
        // st3: Y2 = -xz@Y1 + 15 xz  (planes only)
        mfma_gemm<1, false, true><<<pg, 256, 0, stream>>>(
            xzf, 256, 65536, Y1Th, Y1Tl, 256, 65536,
            nullptr, 256, 65536, Y2Th, Y2Tl, 256, 65536, 256, -1.f, 15.f);
        // st4: zn = -0.25 zc@Y2 + 3.25 zc  -> overwrites xz slot
        mfma_gemm<1, true, true><<<pg, 256, 0, stream>>>(
            zc, 256, 65536, Y2Th, Y2Tl, 256, 65536,
            xzf, 256, 65536, ZTh[1 - cur], ZTl[1 - cur], 256, 65536,
            256, -0.25f, 3.25f);
        cur = 1 - cur;
    }
    float* zfin = Zf[cur];   // == zA

    // t2 = z @ (t1 / rs3)
    gemm_bk<false, true><<<dim3(1, 4, 32), 256, 0, stream>>>(
        zfin, 65536, 256, t1, 16384, 64, t2, 16384, 64, 256, rs3);

    // F1: oh = softmax(q@kland^T)@t2 (in-place over q)
    fused_attn1t2<<<dim3(64, 32), 256, 0, stream>>>(q, kland, t2, q);

    conv_add<<<32768, 256, 0, stream>>>(q, v, w_res);

    mfma_final<<<dim3(4, 128), 256, 0, stream>>>(q, WOTh, WOTl, out);

    (void)in_sizes; (void)n_in; (void)out_size; (void)ws_size;
}

// Round 4
// 1148.396 us; speedup vs baseline: 1.5318x; 1.1297x over previous
//
#include <hip/hip_runtime.h>

// ---------------------------------------------------------------------------
// Nystrom attention: split-bf16 (hi/lo, 3xMFMA) for ALL large GEMMs including
// flash attn kernels. fp32 only for tiny kernels + accumulators.
// B=4, N=4096, DIM=512, H=8, DH=64, M=256, l=16, 6 pinv iters, conv K=33.
// ---------------------------------------------------------------------------

typedef __attribute__((ext_vector_type(8))) short bf16x8;
typedef __attribute__((ext_vector_type(4))) float f32x4;

constexpr size_t SQ = 8388608;   // 32*4096*64
constexpr size_t SL = 524288;    // 32*256*64
constexpr size_t SA = 2097152;   // 32*256*256
constexpr size_t SP = 1048576;   // one bf16 plane of SA (float units)

constexpr size_t O_Q    = 0;                   // q -> later oh (in-place)
constexpr size_t O_K    = O_Q + SQ;            // k -> later zA,zB (f32)
constexpr size_t O_V    = O_K + SQ;
constexpr size_t O_QL   = O_V + SQ;
constexpr size_t O_KL   = O_QL + SL;
constexpr size_t O_A2   = O_KL + SL;
constexpr size_t O_T1   = O_A2 + SA;
constexpr size_t O_RS3  = O_T1 + SL;
constexpr size_t O_SCAL = O_RS3 + 8192;
constexpr size_t O_T2   = O_SCAL + 16;
constexpr size_t O_ZT0  = O_T2 + SL;
constexpr size_t O_ZT1  = O_ZT0 + 2 * SP;      // vT planes alias ZT1..Y2T (pre-pinv)
constexpr size_t O_XZT  = O_ZT1 + 2 * SP;      // t2T planes alias ZT1 (post-pinv)
constexpr size_t O_Y1T  = O_XZT + 2 * SP;
constexpr size_t O_Y2T  = O_Y1T + 2 * SP;
constexpr size_t O_WQT  = O_Y2T + 2 * SP;
constexpr size_t O_WOT  = O_WQT + 786432;
constexpr size_t O_END  = O_WOT + 262144;      // ~41M floats ~164 MB

// ---------------------------------------------------------------------------
__device__ __forceinline__ void split2(float x, unsigned short& h,
                                       unsigned short& l) {
    unsigned u  = __float_as_uint(x);
    unsigned hb = (u + 0x7FFFu + ((u >> 16) & 1u)) & 0xFFFF0000u;  // RNE hi
    h = (unsigned short)(hb >> 16);
    float d = x - __uint_as_float(hb);
    l = (unsigned short)(__float_as_uint(d) >> 16);
}

__device__ __forceinline__ f32x4 mfma3(bf16x8 ah, bf16x8 al, bf16x8 bh,
                                       bf16x8 bl, f32x4 c) {
    c = __builtin_amdgcn_mfma_f32_16x16x32_bf16(ah, bh, c, 0, 0, 0);
    c = __builtin_amdgcn_mfma_f32_16x16x32_bf16(ah, bl, c, 0, 0, 0);
    c = __builtin_amdgcn_mfma_f32_16x16x32_bf16(al, bh, c, 0, 0, 0);
    return c;
}

// split a float4 into hi/lo planes, write packed uint2 at H[off], L[off]
__device__ __forceinline__ void stage_split4(float4 av, unsigned short* H,
                                             unsigned short* L, int off) {
    unsigned short h0, h1, h2, h3, l0, l1, l2, l3;
    split2(av.x, h0, l0); split2(av.y, h1, l1);
    split2(av.z, h2, l2); split2(av.w, h3, l3);
    uint2 ph, pl;
    ph.x = (unsigned)h0 | ((unsigned)h1 << 16);
    ph.y = (unsigned)h2 | ((unsigned)h3 << 16);
    pl.x = (unsigned)l0 | ((unsigned)l1 << 16);
    pl.y = (unsigned)l2 | ((unsigned)l3 << 16);
    *(uint2*)&H[off] = ph;
    *(uint2*)&L[off] = pl;
}

// ---------------------------------------------------------------------------
// pinv-family MFMA GEMM, 64x128 tile: C = alpha*(A@B) + beta*A_elem.
// A fp32 (split in-register); B = transposed bf16 planes BT[n][k].
// grid (N/128=2, M/64=4, 32), block 256.
// ---------------------------------------------------------------------------
template <int EPI, bool WF32, bool WT>
__global__ __launch_bounds__(256) void mfma_gemm(
    const float* __restrict__ A, int lda, long saA,
    const unsigned short* __restrict__ BTh,
    const unsigned short* __restrict__ BTl, int ldbt, long sbT,
    float* __restrict__ C, int ldc, long scC,
    unsigned short* __restrict__ CTh, unsigned short* __restrict__ CTl,
    int ldct, long sct, int K, float alpha, float beta) {
    __shared__ unsigned short Ah[64 * 40], Al[64 * 40];
    __shared__ unsigned short Bh[128 * 40], Bl[128 * 40];
    const int t = threadIdx.x;
    const int wave = t >> 6, lane = t & 63, lm = lane & 15, lq = lane >> 4;
    const int z = blockIdx.z;
    const int m0 = blockIdx.y * 64, n0 = blockIdx.x * 128;
    const float* Ab = A + (size_t)z * saA;
    const unsigned short* BhB = BTh + (size_t)z * sbT;
    const unsigned short* BlB = BTl + (size_t)z * sbT;

    f32x4 acc[8];
#pragma unroll
    for (int j = 0; j < 8; ++j) acc[j] = (f32x4){0.f, 0.f, 0.f, 0.f};

    for (int kt = 0; kt < K; kt += 32) {
#pragma unroll
        for (int r = 0; r < 2; ++r) {
            int id = t + r * 256, row = id >> 3, k4 = (id & 7) * 4;
            float4 av = *(const float4*)(Ab + (size_t)(m0 + row) * lda + kt + k4);
            stage_split4(av, Ah, Al, row * 40 + k4);
        }
#pragma unroll
        for (int r = 0; r < 2; ++r) {
            int id = t + r * 256, row = id >> 2, ko = (id & 3) * 8;
            *(uint4*)&Bh[row * 40 + ko] =
                *(const uint4*)(BhB + (size_t)(n0 + row) * ldbt + kt + ko);
            *(uint4*)&Bl[row * 40 + ko] =
                *(const uint4*)(BlB + (size_t)(n0 + row) * ldbt + kt + ko);
        }
        __syncthreads();
        bf16x8 ah = *(const bf16x8*)&Ah[(wave * 16 + lm) * 40 + lq * 8];
        bf16x8 al = *(const bf16x8*)&Al[(wave * 16 + lm) * 40 + lq * 8];
#pragma unroll
        for (int j = 0; j < 8; ++j) {
            bf16x8 bh = *(const bf16x8*)&Bh[(j * 16 + lm) * 40 + lq * 8];
            bf16x8 bl = *(const bf16x8*)&Bl[(j * 16 + lm) * 40 + lq * 8];
            acc[j] = mfma3(ah, al, bh, bl, acc[j]);
        }
        __syncthreads();
    }

    float* Cb = C + (size_t)z * scC;
    unsigned short* CThB = CTh + (size_t)z * sct;
    unsigned short* CTlB = CTl + (size_t)z * sct;
    const int r0 = m0 + wave * 16 + lq * 4;
#pragma unroll
    for (int j = 0; j < 8; ++j) {
        int c = n0 + j * 16 + lm;
        float vals[4] = {acc[j][0], acc[j][1], acc[j][2], acc[j][3]};
        if (EPI == 1) {
#pragma unroll
            for (int e = 0; e < 4; ++e)
                vals[e] = alpha * vals[e] + beta * Ab[(size_t)(r0 + e) * lda + c];
        }
        if (WF32) {
#pragma unroll
            for (int e = 0; e < 4; ++e)
                Cb[(size_t)(r0 + e) * ldc + c] = vals[e];
        }
        if (WT) {
            unsigned short hh[4], ll[4];
#pragma unroll
            for (int e = 0; e < 4; ++e) split2(vals[e], hh[e], ll[e]);
            uint2 ph, pl;
            ph.x = (unsigned)hh[0] | ((unsigned)hh[1] << 16);
            ph.y = (unsigned)hh[2] | ((unsigned)hh[3] << 16);
            pl.x = (unsigned)ll[0] | ((unsigned)ll[1] << 16);
            pl.y = (unsigned)ll[2] | ((unsigned)ll[3] << 16);
            *(uint2*)&CThB[(size_t)c * ldct + r0] = ph;
            *(uint2*)&CTlB[(size_t)c * ldct + r0] = pl;
        }
    }
}

// ---------------------------------------------------------------------------
// qkv MFMA GEMM: x[16384,512] @ w_qkv planes; scatters q(*0.125)/k/v AND
// emits vT split-bf16 planes [bh][dh][4096].  grid (12, 128).
// ---------------------------------------------------------------------------
__global__ __launch_bounds__(256) void mfma_qkv(
    const float* __restrict__ X, const unsigned short* __restrict__ WTh,
    const unsigned short* __restrict__ WTl, float* __restrict__ qb,
    float* __restrict__ kb, float* __restrict__ vb,
    unsigned short* __restrict__ vTh, unsigned short* __restrict__ vTl) {
    __shared__ unsigned short Ah[128 * 40], Al[128 * 40];
    __shared__ unsigned short Bh[128 * 40], Bl[128 * 40];
    const int t = threadIdx.x;
    const int wave = t >> 6, lane = t & 63, lm = lane & 15, lq = lane >> 4;
    const int m0 = blockIdx.y * 128, n0 = blockIdx.x * 128;
    const int mb = (wave >> 1) * 64, nb = (wave & 1) * 64;
    f32x4 acc[4][4];
#pragma unroll
    for (int i = 0; i < 4; ++i)
#pragma unroll
        for (int j = 0; j < 4; ++j) acc[i][j] = (f32x4){0.f, 0.f, 0.f, 0.f};

    for (int kt = 0; kt < 512; kt += 32) {
#pragma unroll
        for (int r = 0; r < 4; ++r) {
            int id = t + r * 256, row = id >> 3, k4 = (id & 7) * 4;
            float4 av = *(const float4*)(X + (size_t)(m0 + row) * 512 + kt + k4);
            stage_split4(av, Ah, Al, row * 40 + k4);
        }
#pragma unroll
        for (int r = 0; r < 2; ++r) {
            int id = t + r * 256, row = id >> 2, ko = (id & 3) * 8;
            *(uint4*)&Bh[row * 40 + ko] =
                *(const uint4*)(WTh + (size_t)(n0 + row) * 512 + kt + ko);
            *(uint4*)&Bl[row * 40 + ko] =
                *(const uint4*)(WTl + (size_t)(n0 + row) * 512 + kt + ko);
        }
        __syncthreads();
        bf16x8 ah[4], al[4], bh[4], bl[4];
#pragma unroll
        for (int i = 0; i < 4; ++i) {
            ah[i] = *(const bf16x8*)&Ah[(mb + i * 16 + lm) * 40 + lq * 8];
            al[i] = *(const bf16x8*)&Al[(mb + i * 16 + lm) * 40 + lq * 8];
        }
#pragma unroll
        for (int j = 0; j < 4; ++j) {
            bh[j] = *(const bf16x8*)&Bh[(nb + j * 16 + lm) * 40 + lq * 8];
            bl[j] = *(const bf16x8*)&Bl[(nb + j * 16 + lm) * 40 + lq * 8];
        }
#pragma unroll
        for (int i = 0; i < 4; ++i)
#pragma unroll
            for (int j = 0; j < 4; ++j)
                acc[i][j] = mfma3(ah[i], al[i], bh[j], bl[j], acc[i][j]);
        __syncthreads();
    }
#pragma unroll
    for (int i = 0; i < 4; ++i)
#pragma unroll
        for (int j = 0; j < 4; ++j) {
            int r0 = m0 + mb + i * 16 + lq * 4;
            int c  = n0 + nb + j * 16 + lm;
            int which = c >> 9, h = (c >> 6) & 7, d = c & 63;
            float sc = (which == 0) ? 0.125f : 1.0f;
            float* dst = (which == 0) ? qb : (which == 1 ? kb : vb);
            int b = r0 >> 12, nbase = r0 & 4095;
#pragma unroll
            for (int e = 0; e < 4; ++e)
                dst[(size_t)(b * 8 + h) * 262144 + (size_t)(nbase + e) * 64 + d] =
                    acc[i][j][e] * sc;
            if (which == 2) {
                unsigned short hh[4], ll[4];
#pragma unroll
                for (int e = 0; e < 4; ++e) split2(acc[i][j][e], hh[e], ll[e]);
                uint2 ph, pl;
                ph.x = (unsigned)hh[0] | ((unsigned)hh[1] << 16);
                ph.y = (unsigned)hh[2] | ((unsigned)hh[3] << 16);
                pl.x = (unsigned)ll[0] | ((unsigned)ll[1] << 16);
                pl.y = (unsigned)ll[2] | ((unsigned)ll[3] << 16);
                size_t off = ((size_t)(b * 8 + h) * 64 + d) * 4096 + nbase;
                *(uint2*)&vTh[off] = ph;
                *(uint2*)&vTl[off] = pl;
            }
        }
}

// ---------------------------------------------------------------------------
// final MFMA GEMM: out[16384,512] = oh(gathered) @ w_out planes. grid (4,128)
// ---------------------------------------------------------------------------
__global__ __launch_bounds__(256) void mfma_final(
    const float* __restrict__ OH, const unsigned short* __restrict__ WTh,
    const unsigned short* __restrict__ WTl, float* __restrict__ out) {
    __shared__ unsigned short Ah[128 * 40], Al[128 * 40];
    __shared__ unsigned short Bh[128 * 40], Bl[128 * 40];
    const int t = threadIdx.x;
    const int wave = t >> 6, lane = t & 63, lm = lane & 15, lq = lane >> 4;
    const int m0 = blockIdx.y * 128, n0 = blockIdx.x * 128;
    const int mb = (wave >> 1) * 64, nb = (wave & 1) * 64;
    f32x4 acc[4][4];
#pragma unroll
    for (int i = 0; i < 4; ++i)
#pragma unroll
        for (int j = 0; j < 4; ++j) acc[i][j] = (f32x4){0.f, 0.f, 0.f, 0.f};

    for (int kt = 0; kt < 512; kt += 32) {
#pragma unroll
        for (int r = 0; r < 4; ++r) {
            int id = t + r * 256, row = id >> 3, k4g = kt + (id & 7) * 4;
            int gr = m0 + row, b = gr >> 12, n = gr & 4095;
            float4 av = *(const float4*)(OH + (size_t)(b * 8 + (k4g >> 6)) * 262144 +
                                         (size_t)n * 64 + (k4g & 63));
            stage_split4(av, Ah, Al, row * 40 + (id & 7) * 4);
        }
#pragma unroll
        for (int r = 0; r < 2; ++r) {
            int id = t + r * 256, row = id >> 2, ko = (id & 3) * 8;
            *(uint4*)&Bh[row * 40 + ko] =
                *(const uint4*)(WTh + (size_t)(n0 + row) * 512 + kt + ko);
            *(uint4*)&Bl[row * 40 + ko] =
                *(const uint4*)(WTl + (size_t)(n0 + row) * 512 + kt + ko);
        }
        __syncthreads();
        bf16x8 ah[4], al[4], bh[4], bl[4];
#pragma unroll
        for (int i = 0; i < 4; ++i) {
            ah[i] = *(const bf16x8*)&Ah[(mb + i * 16 + lm) * 40 + lq * 8];
            al[i] = *(const bf16x8*)&Al[(mb + i * 16 + lm) * 40 + lq * 8];
        }
#pragma unroll
        for (int j = 0; j < 4; ++j) {
            bh[j] = *(const bf16x8*)&Bh[(nb + j * 16 + lm) * 40 + lq * 8];
            bl[j] = *(const bf16x8*)&Bl[(nb + j * 16 + lm) * 40 + lq * 8];
        }
#pragma unroll
        for (int i = 0; i < 4; ++i)
#pragma unroll
            for (int j = 0; j < 4; ++j)
                acc[i][j] = mfma3(ah[i], al[i], bh[j], bl[j], acc[i][j]);
        __syncthreads();
    }
#pragma unroll
    for (int i = 0; i < 4; ++i)
#pragma unroll
        for (int j = 0; j < 4; ++j) {
            int r0 = m0 + mb + i * 16 + lq * 4;
            int c  = n0 + nb + j * 16 + lm;
#pragma unroll
            for (int e = 0; e < 4; ++e)
                out[(size_t)(r0 + e) * 512 + c] = acc[i][j][e];
        }
}

// ---------------------------------------------------------------------------
// F3 MFMA: t1 += exp(qland@k^T)@v, rs3 += rowsums. grid (8, 4, 32).
// LDS: Q(64x72), K/V(64x72), E(64x72) split planes = 55.3 KB.
// ---------------------------------------------------------------------------
__global__ __launch_bounds__(256) void attn3v_mfma(
    const float* __restrict__ qland, const float* __restrict__ k,
    const unsigned short* __restrict__ vTh,
    const unsigned short* __restrict__ vTl,
    float* __restrict__ t1, float* __restrict__ rs3) {
    __shared__ unsigned short Qh[4608], Ql[4608];
    __shared__ unsigned short Kh[4608], Kl[4608];
    __shared__ unsigned short Eh[4608], El[4608];
    const int t = threadIdx.x;
    const int wave = t >> 6, lane = t & 63, lm = lane & 15, lq = lane >> 4;
    const int bz = blockIdx.z, m0 = blockIdx.y * 64, c0 = blockIdx.x * 8;
    const float* qb = qland + (size_t)bz * 16384;
    const float* kb = k + (size_t)bz * 262144;
    const unsigned short* vhb = vTh + (size_t)bz * 262144;
    const unsigned short* vlb = vTl + (size_t)bz * 262144;
#pragma unroll
    for (int r = 0; r < 4; ++r) {
        int id = t + r * 256, row = id >> 4, d4 = (id & 15) * 4;
        float4 av = *(const float4*)(qb + (size_t)(m0 + row) * 64 + d4);
        stage_split4(av, Qh, Ql, row * 72 + d4);
    }
    f32x4 acc[4];
#pragma unroll
    for (int j = 0; j < 4; ++j) acc[j] = (f32x4){0.f, 0.f, 0.f, 0.f};
    float rsum[4] = {0.f, 0.f, 0.f, 0.f};
    __syncthreads();

    for (int c = c0; c < c0 + 8; ++c) {
        const int tok0 = c * 64;
#pragma unroll
        for (int r = 0; r < 4; ++r) {
            int id = t + r * 256, row = id >> 4, d4 = (id & 15) * 4;
            float4 kv = *(const float4*)(kb + (size_t)(tok0 + row) * 64 + d4);
            stage_split4(kv, Kh, Kl, row * 72 + d4);
        }
        __syncthreads();
        bf16x8 a0  = *(const bf16x8*)&Qh[(wave * 16 + lm) * 72 + lq * 8];
        bf16x8 a0l = *(const bf16x8*)&Ql[(wave * 16 + lm) * 72 + lq * 8];
        bf16x8 a1  = *(const bf16x8*)&Qh[(wave * 16 + lm) * 72 + 32 + lq * 8];
        bf16x8 a1l = *(const bf16x8*)&Ql[(wave * 16 + lm) * 72 + 32 + lq * 8];
        f32x4 s[4];
#pragma unroll
        for (int j = 0; j < 4; ++j) s[j] = (f32x4){0.f, 0.f, 0.f, 0.f};
#pragma unroll
        for (int j = 0; j < 4; ++j) {
            bf16x8 b0  = *(const bf16x8*)&Kh[(j * 16 + lm) * 72 + lq * 8];
            bf16x8 b0l = *(const bf16x8*)&Kl[(j * 16 + lm) * 72 + lq * 8];
            bf16x8 b1  = *(const bf16x8*)&Kh[(j * 16 + lm) * 72 + 32 + lq * 8];
            bf16x8 b1l = *(const bf16x8*)&Kl[(j * 16 + lm) * 72 + 32 + lq * 8];
            s[j] = mfma3(a0, a0l, b0, b0l, s[j]);
            s[j] = mfma3(a1, a1l, b1, b1l, s[j]);
        }
        __syncthreads();
#pragma unroll
        for (int j = 0; j < 4; ++j)
#pragma unroll
            for (int e = 0; e < 4; ++e) {
                float ev = __expf(s[j][e]);
                rsum[e] += ev;
                unsigned short h, l;
                split2(ev, h, l);
                int off = (wave * 16 + lq * 4 + e) * 72 + j * 16 + lm;
                Eh[off] = h;
                El[off] = l;
            }
#pragma unroll
        for (int r = 0; r < 2; ++r) {
            int id = t + r * 256, dh = id >> 3, t8 = (id & 7) * 8;
            *(uint4*)&Kh[dh * 72 + t8] =
                *(const uint4*)(vhb + (size_t)dh * 4096 + tok0 + t8);
            *(uint4*)&Kl[dh * 72 + t8] =
                *(const uint4*)(vlb + (size_t)dh * 4096 + tok0 + t8);
        }
        __syncthreads();
        bf16x8 e0  = *(const bf16x8*)&Eh[(wave * 16 + lm) * 72 + lq * 8];
        bf16x8 e0l = *(const bf16x8*)&El[(wave * 16 + lm) * 72 + lq * 8];
        bf16x8 e1  = *(const bf16x8*)&Eh[(wave * 16 + lm) * 72 + 32 + lq * 8];
        bf16x8 e1l = *(const bf16x8*)&El[(wave * 16 + lm) * 72 + 32 + lq * 8];
#pragma unroll
        for (int j = 0; j < 4; ++j) {
            bf16x8 v0  = *(const bf16x8*)&Kh[(j * 16 + lm) * 72 + lq * 8];
            bf16x8 v0l = *(const bf16x8*)&Kl[(j * 16 + lm) * 72 + lq * 8];
            bf16x8 v1  = *(const bf16x8*)&Kh[(j * 16 + lm) * 72 + 32 + lq * 8];
            bf16x8 v1l = *(const bf16x8*)&Kl[(j * 16 + lm) * 72 + 32 + lq * 8];
            acc[j] = mfma3(e0, e0l, v0, v0l, acc[j]);
            acc[j] = mfma3(e1, e1l, v1, v1l, acc[j]);
        }
        __syncthreads();
    }
    float* t1b = t1 + (size_t)bz * 16384;
#pragma unroll
    for (int j = 0; j < 4; ++j)
#pragma unroll
        for (int e = 0; e < 4; ++e)
            atomicAdd(t1b + (size_t)(m0 + wave * 16 + lq * 4 + e) * 64 +
                          j * 16 + lm,
                      acc[j][e]);
#pragma unroll
    for (int e = 0; e < 4; ++e) {
        float vs = rsum[e];
        for (int mm = 1; mm < 16; mm <<= 1) vs += __shfl_xor(vs, mm);
        if (lm == 0)
            atomicAdd(rs3 + bz * 256 + m0 + wave * 16 + lq * 4 + e, vs);
    }
}

// ---------------------------------------------------------------------------
// F1 MFMA: oh = softmax(q@kland^T) @ t2 (normalized), in-place over q.
// grid (64, 32).
// ---------------------------------------------------------------------------
__global__ __launch_bounds__(256) void attn1t2_mfma(
    const float* __restrict__ q, const float* __restrict__ kland,
    const unsigned short* __restrict__ t2Th,
    const unsigned short* __restrict__ t2Tl, float* __restrict__ oh) {
    __shared__ unsigned short Qh[4608], Ql[4608];
    __shared__ unsigned short Kh[4608], Kl[4608];
    __shared__ unsigned short Eh[4608], El[4608];
    const int t = threadIdx.x;
    const int wave = t >> 6, lane = t & 63, lm = lane & 15, lq = lane >> 4;
    const int bz = blockIdx.y, m0 = blockIdx.x * 64;
    const float* qb  = q + (size_t)bz * 262144;
    const float* klb = kland + (size_t)bz * 16384;
    const unsigned short* t2h = t2Th + (size_t)bz * 16384;
    const unsigned short* t2l = t2Tl + (size_t)bz * 16384;
#pragma unroll
    for (int r = 0; r < 4; ++r) {
        int id = t + r * 256, row = id >> 4, d4 = (id & 15) * 4;
        float4 av = *(const float4*)(qb + (size_t)(m0 + row) * 64 + d4);
        stage_split4(av, Qh, Ql, row * 72 + d4);
    }
    f32x4 acc[4];
#pragma unroll
    for (int j = 0; j < 4; ++j) acc[j] = (f32x4){0.f, 0.f, 0.f, 0.f};
    float rsum[4] = {0.f, 0.f, 0.f, 0.f};
    __syncthreads();

    for (int lc = 0; lc < 4; ++lc) {
        const int l0 = lc * 64;
#pragma unroll
        for (int r = 0; r < 4; ++r) {
            int id = t + r * 256, row = id >> 4, d4 = (id & 15) * 4;
            float4 kv = *(const float4*)(klb + (size_t)(l0 + row) * 64 + d4);
            stage_split4(kv, Kh, Kl, row * 72 + d4);
        }
        __syncthreads();
        bf16x8 a0  = *(const bf16x8*)&Qh[(wave * 16 + lm) * 72 + lq * 8];
        bf16x8 a0l = *(const bf16x8*)&Ql[(wave * 16 + lm) * 72 + lq * 8];
        bf16x8 a1  = *(const bf16x8*)&Qh[(wave * 16 + lm) * 72 + 32 + lq * 8];
        bf16x8 a1l = *(const bf16x8*)&Ql[(wave * 16 + lm) * 72 + 32 + lq * 8];
        f32x4 s[4];
#pragma unroll
        for (int j = 0; j < 4; ++j) s[j] = (f32x4){0.f, 0.f, 0.f, 0.f};
#pragma unroll
        for (int j = 0; j < 4; ++j) {
            bf16x8 b0  = *(const bf16x8*)&Kh[(j * 16 + lm) * 72 + lq * 8];
            bf16x8 b0l = *(const bf16x8*)&Kl[(j * 16 + lm) * 72 + lq * 8];
            bf16x8 b1  = *(const bf16x8*)&Kh[(j * 16 + lm) * 72 + 32 + lq * 8];
            bf16x8 b1l = *(const bf16x8*)&Kl[(j * 16 + lm) * 72 + 32 + lq * 8];
            s[j] = mfma3(a0, a0l, b0, b0l, s[j]);
            s[j] = mfma3(a1, a1l, b1, b1l, s[j]);
        }
        __syncthreads();
#pragma unroll
        for (int j = 0; j < 4; ++j)
#pragma unroll
            for (int e = 0; e < 4; ++e) {
                float ev = __expf(s[j][e]);
                rsum[e] += ev;
                unsigned short h, l;
                split2(ev, h, l);
                int off = (wave * 16 + lq * 4 + e) * 72 + j * 16 + lm;
                Eh[off] = h;
                El[off] = l;
            }
#pragma unroll
        for (int r = 0; r < 2; ++r) {
            int id = t + r * 256, dh = id >> 3, t8 = (id & 7) * 8;
            *(uint4*)&Kh[dh * 72 + t8] =
                *(const uint4*)(t2h + (size_t)dh * 256 + l0 + t8);
            *(uint4*)&Kl[dh * 72 + t8] =
                *(const uint4*)(t2l + (size_t)dh * 256 + l0 + t8);
        }
        __syncthreads();
        bf16x8 e0  = *(const bf16x8*)&Eh[(wave * 16 + lm) * 72 + lq * 8];
        bf16x8 e0l = *(const bf16x8*)&El[(wave * 16 + lm) * 72 + lq * 8];
        bf16x8 e1  = *(const bf16x8*)&Eh[(wave * 16 + lm) * 72 + 32 + lq * 8];
        bf16x8 e1l = *(const bf16x8*)&El[(wave * 16 + lm) * 72 + 32 + lq * 8];
#pragma unroll
        for (int j = 0; j < 4; ++j) {
            bf16x8 v0  = *(const bf16x8*)&Kh[(j * 16 + lm) * 72 + lq * 8];
            bf16x8 v0l = *(const bf16x8*)&Kl[(j * 16 + lm) * 72 + lq * 8];
            bf16x8 v1  = *(const bf16x8*)&Kh[(j * 16 + lm) * 72 + 32 + lq * 8];
            bf16x8 v1l = *(const bf16x8*)&Kl[(j * 16 + lm) * 72 + 32 + lq * 8];
            acc[j] = mfma3(e0, e0l, v0, v0l, acc[j]);
            acc[j] = mfma3(e1, e1l, v1, v1l, acc[j]);
        }
        __syncthreads();
    }
    float rinv[4];
#pragma unroll
    for (int e = 0; e < 4; ++e) {
        float vs = rsum[e];
        for (int mm = 1; mm < 16; mm <<= 1) vs += __shfl_xor(vs, mm);
        rinv[e] = 1.0f / vs;
    }
    float* ohb = oh + (size_t)bz * 262144;
#pragma unroll
    for (int j = 0; j < 4; ++j)
#pragma unroll
        for (int e = 0; e < 4; ++e)
            ohb[(size_t)(m0 + wave * 16 + lq * 4 + e) * 64 + j * 16 + lm] =
                acc[j][e] * rinv[e];
}

// ---------------------------------------------------------------------------
// weight transpose+split: W[512][N] -> planes T[N][512]
// ---------------------------------------------------------------------------
__global__ void wtrans(const float* __restrict__ W, int N,
                       unsigned short* __restrict__ Th,
                       unsigned short* __restrict__ Tl) {
    int idx = blockIdx.x * 256 + threadIdx.x;
    int n = idx >> 9, kk = idx & 511;
    float x = W[(size_t)kk * N + n];
    unsigned short h, l;
    split2(x, h, l);
    Th[idx] = h;
    Tl[idx] = l;
}

// ---------------------------------------------------------------------------
// fp32 64x64 micro-kernel + gemm_bk (attn2 + t2 only)
// ---------------------------------------------------------------------------
__device__ __forceinline__ void mt16(const float* As, const float* Bs,
                                     int ty4, int tx4, float (&acc)[4][4]) {
#pragma unroll
    for (int kk = 0; kk < 16; ++kk) {
        float4 a4 = *(const float4*)(As + kk * 68 + ty4);
        float4 b4 = *(const float4*)(Bs + kk * 68 + tx4);
        float aa[4] = {a4.x, a4.y, a4.z, a4.w};
        float bb[4] = {b4.x, b4.y, b4.z, b4.w};
#pragma unroll
        for (int u = 0; u < 4; ++u)
#pragma unroll
            for (int w = 0; w < 4; ++w)
                acc[u][w] += aa[u] * bb[w];
    }
}

template <bool TRANSB, bool DIVB, bool WTOUT>
__global__ __launch_bounds__(256) void gemm_bk(
    const float* __restrict__ A, int saA, int lda,
    const float* __restrict__ B, int sbB, int ldb,
    float* __restrict__ C, int scC, int ldc,
    int K, const float* __restrict__ divv,
    unsigned short* __restrict__ CTh, unsigned short* __restrict__ CTl) {
    __shared__ float As[16 * 68];
    __shared__ float Bs[16 * 68];
    const int t  = threadIdx.x;
    const int z  = blockIdx.z;
    const int m0 = blockIdx.y * 64;
    const int n0 = blockIdx.x * 64;
    const float* Ab = A + (size_t)z * saA;
    const float* Bb = B + (size_t)z * sbB;
    float*       Cb = C + (size_t)z * scC;
    const int tx4 = (t & 15) * 4;
    const int ty4 = (t >> 4) * 4;
    const int ar  = t >> 2, ak = (t & 3) * 4;
    const int bkr = t >> 4, bc4 = (t & 15) * 4;
    float acc[4][4] = {};
    for (int kt = 0; kt < K; kt += 16) {
        float4 av = *(const float4*)(Ab + (size_t)(m0 + ar) * lda + kt + ak);
        float4 bv;
        if (TRANSB) {
            bv = *(const float4*)(Bb + (size_t)(n0 + ar) * ldb + kt + ak);
        } else {
            bv = *(const float4*)(Bb + (size_t)(kt + bkr) * ldb + n0 + bc4);
            if (DIVB) {
                float r = 1.0f / divv[z * K + kt + bkr];
                bv.x *= r; bv.y *= r; bv.z *= r; bv.w *= r;
            }
        }
        As[(ak + 0) * 68 + ar] = av.x;
        As[(ak + 1) * 68 + ar] = av.y;
        As[(ak + 2) * 68 + ar] = av.z;
        As[(ak + 3) * 68 + ar] = av.w;
        if (TRANSB) {
            Bs[(ak + 0) * 68 + ar] = bv.x;
            Bs[(ak + 1) * 68 + ar] = bv.y;
            Bs[(ak + 2) * 68 + ar] = bv.z;
            Bs[(ak + 3) * 68 + ar] = bv.w;
        } else {
            *(float4*)(Bs + bkr * 68 + bc4) = bv;
        }
        __syncthreads();
        mt16(As, Bs, ty4, tx4, acc);
        __syncthreads();
    }
#pragma unroll
    for (int u = 0; u < 4; ++u) {
        int row = m0 + ty4 + u;
        *(float4*)(Cb + (size_t)row * ldc + n0 + tx4) =
            make_float4(acc[u][0], acc[u][1], acc[u][2], acc[u][3]);
    }
    if (WTOUT) {
        // write C^T split planes: CT[col][row], 4 consecutive rows packed
#pragma unroll
        for (int w = 0; w < 4; ++w) {
            unsigned short hh[4], ll[4];
#pragma unroll
            for (int u = 0; u < 4; ++u) split2(acc[u][w], hh[u], ll[u]);
            uint2 ph, pl;
            ph.x = (unsigned)hh[0] | ((unsigned)hh[1] << 16);
            ph.y = (unsigned)hh[2] | ((unsigned)hh[3] << 16);
            pl.x = (unsigned)ll[0] | ((unsigned)ll[1] << 16);
            pl.y = (unsigned)ll[2] | ((unsigned)ll[3] << 16);
            size_t off = (size_t)z * 16384 + (size_t)(n0 + tx4 + w) * 256 +
                         m0 + ty4;
            *(uint2*)&CTh[off] = ph;
            *(uint2*)&CTl[off] = pl;
        }
    }
}

// ---------------------------------------------------------------------------
// small kernels
// ---------------------------------------------------------------------------
__global__ void zero_f(float* __restrict__ p, int n) {
    int i = blockIdx.x * 256 + threadIdx.x;
    if (i < n) p[i] = 0.f;
}

__global__ void landmark_mean(const float* __restrict__ src,
                              float* __restrict__ dst) {
    int o = blockIdx.x * 256 + threadIdx.x;
    int d = o & 63, m = (o >> 6) & 255, bh = o >> 14;
    const float* s = src + (size_t)bh * 262144 + (size_t)m * 1024 + d;
    float acc = 0.f;
#pragma unroll
    for (int j = 0; j < 16; ++j) acc += s[j * 64];
    dst[o] = acc * (1.0f / 16.0f);
}

__global__ void softmax_rows(float* __restrict__ a) {
    __shared__ float red[256];
    int row = blockIdx.x, t = threadIdx.x;
    float v = a[(size_t)row * 256 + t];
    red[t] = v;
    __syncthreads();
    for (int s = 128; s > 0; s >>= 1) {
        if (t < s) red[t] = fmaxf(red[t], red[t + s]);
        __syncthreads();
    }
    float mx = red[0];
    __syncthreads();
    float e = __expf(v - mx);
    red[t] = e;
    __syncthreads();
    for (int s = 128; s > 0; s >>= 1) {
        if (t < s) red[t] += red[t + s];
        __syncthreads();
    }
    a[(size_t)row * 256 + t] = e / red[0];
}

__global__ __launch_bounds__(256) void scalar_prep(const float* __restrict__ a,
                                                   float* __restrict__ scal) {
    __shared__ float red[256];
    int bh = blockIdx.x, t = threadIdx.x;
    const float* ab = a + (size_t)bh * 65536;
    float cs = 0.f;
    for (int i = 0; i < 256; ++i) cs += ab[i * 256 + t];
    red[t] = cs;
    __syncthreads();
    for (int s = 128; s > 0; s >>= 1) {
        if (t < s) red[t] = fmaxf(red[t], red[t + s]);
        __syncthreads();
    }
    float mcol = red[0];
    __syncthreads();
    float rs = 0.f;
    for (int j = 0; j < 256; ++j) rs += ab[t * 256 + j];
    red[t] = rs;
    __syncthreads();
    for (int s = 128; s > 0; s >>= 1) {
        if (t < s) red[t] = fmaxf(red[t], red[t + s]);
        __syncthreads();
    }
    if (t == 0) {
        atomicMax((unsigned int*)&scal[0], __float_as_uint(mcol));
        atomicMax((unsigned int*)&scal[1], __float_as_uint(red[0]));
    }
}

__global__ void zinit(const float* __restrict__ a, float* __restrict__ zz,
                      unsigned short* __restrict__ zTh,
                      unsigned short* __restrict__ zTl,
                      const float* __restrict__ scal) {
    int idx = blockIdx.x * 256 + threadIdx.x;
    int bh = idx >> 16, r = (idx >> 8) & 255, c = idx & 255;
    float denom = scal[0] * scal[1] + 1e-8f;
    float v = a[idx] / denom;
    zz[((size_t)bh << 16) + ((size_t)c << 8) + r] = v;
    unsigned short h, l;
    split2(v, h, l);
    zTh[idx] = h;
    zTl[idx] = l;
}

__global__ __launch_bounds__(256) void conv_add(
    float* __restrict__ oh, const float* __restrict__ v,
    const float* __restrict__ wres) {
    int idx = blockIdx.x * 256 + threadIdx.x;
    int d = idx & 63, n = (idx >> 6) & 4095, bh = idx >> 18;
    int h = bh & 7;
    float acc = oh[idx];
    const float* vb = v + (size_t)bh * 262144 + d;
    const float* wb = wres + h * 33;
#pragma unroll
    for (int tt = 0; tt < 33; ++tt) {
        int j = n + tt - 16;
        if ((unsigned)j < 4096u) acc += vb[(size_t)j * 64] * wb[tt];
    }
    oh[idx] = acc;
}

// ---------------------------------------------------------------------------
extern "C" void kernel_launch(void* const* d_in, const int* in_sizes, int n_in,
                              void* d_out, int out_size, void* d_ws, size_t ws_size,
                              hipStream_t stream) {
    const float* x     = (const float*)d_in[0];
    const float* w_qkv = (const float*)d_in[1];
    const float* w_out = (const float*)d_in[2];
    const float* w_res = (const float*)d_in[3];
    float* out = (float*)d_out;
    float* ws  = (float*)d_ws;

    float* q     = ws + O_Q;
    float* k     = ws + O_K;
    float* v     = ws + O_V;
    float* qland = ws + O_QL;
    float* kland = ws + O_KL;
    float* attn2 = ws + O_A2;
    float* t1    = ws + O_T1;
    float* rs3   = ws + O_RS3;
    float* scal  = ws + O_SCAL;
    float* t2    = ws + O_T2;
    float* zA    = k;
    float* zB    = k + SA;

    unsigned short* ZT0h = (unsigned short*)(ws + O_ZT0);
    unsigned short* ZT0l = (unsigned short*)(ws + O_ZT0 + SP);
    unsigned short* ZT1h = (unsigned short*)(ws + O_ZT1);
    unsigned short* ZT1l = (unsigned short*)(ws + O_ZT1 + SP);
    unsigned short* XZTh = (unsigned short*)(ws + O_XZT);
    unsigned short* XZTl = (unsigned short*)(ws + O_XZT + SP);
    unsigned short* Y1Th = (unsigned short*)(ws + O_Y1T);
    unsigned short* Y1Tl = (unsigned short*)(ws + O_Y1T + SP);
    unsigned short* Y2Th = (unsigned short*)(ws + O_Y2T);
    unsigned short* Y2Tl = (unsigned short*)(ws + O_Y2T + SP);
    unsigned short* WQTh = (unsigned short*)(ws + O_WQT);
    unsigned short* WQTl = (unsigned short*)(ws + O_WQT + 393216);
    unsigned short* WOTh = (unsigned short*)(ws + O_WOT);
    unsigned short* WOTl = (unsigned short*)(ws + O_WOT + 131072);
    // vT split planes alias ZT1..Y2T (8 SP exactly); dead before zinit.
    unsigned short* vTh = (unsigned short*)(ws + O_ZT1);
    unsigned short* vTl = vTh + 8388608;
    // t2T planes alias ZT1 after pinv.
    unsigned short* t2Th = (unsigned short*)(ws + O_ZT1);
    unsigned short* t2Tl = t2Th + 524288;

    zero_f<<<2081, 256, 0, stream>>>(t1, 532496);   // t1+rs3+scal
    wtrans<<<3072, 256, 0, stream>>>(w_qkv, 1536, WQTh, WQTl);
    wtrans<<<1024, 256, 0, stream>>>(w_out, 512, WOTh, WOTl);

    mfma_qkv<<<dim3(12, 128), 256, 0, stream>>>(x, WQTh, WQTl, q, k, v,
                                                vTh, vTl);

    landmark_mean<<<2048, 256, 0, stream>>>(q, qland);
    landmark_mean<<<2048, 256, 0, stream>>>(k, kland);

    gemm_bk<true, false, false><<<dim3(4, 4, 32), 256, 0, stream>>>(
        qland, 16384, 64, kland, 16384, 64, attn2, 65536, 256, 64, nullptr,
        nullptr, nullptr);
    softmax_rows<<<8192, 256, 0, stream>>>(attn2);
    scalar_prep<<<32, 256, 0, stream>>>(attn2, scal);

    // F3 before pinv (k and vT planes die here)
    attn3v_mfma<<<dim3(8, 4, 32), 256, 0, stream>>>(qland, k, vTh, vTl, t1, rs3);

    zinit<<<8192, 256, 0, stream>>>(attn2, zA, ZT0h, ZT0l, scal);

    unsigned short* ZTh[2] = {ZT0h, ZT1h};
    unsigned short* ZTl[2] = {ZT0l, ZT1l};
    float* Zf[2] = {zA, zB};
    int cur = 0;
    const dim3 pg(2, 4, 32);
    for (int it = 0; it < 6; ++it) {
        float* zc  = Zf[cur];
        float* xzf = Zf[1 - cur];
        mfma_gemm<0, true, true><<<pg, 256, 0, stream>>>(
            attn2, 256, 65536, ZTh[cur], ZTl[cur], 256, 65536,
            xzf, 256, 65536, XZTh, XZTl, 256, 65536, 256, 0.f, 0.f);
        mfma_gemm<1, false, true><<<pg, 256, 0, stream>>>(
            xzf, 256, 65536, XZTh, XZTl, 256, 65536,
            nullptr, 256, 65536, Y1Th, Y1Tl, 256, 65536, 256, -1.f, 7.f);
        mfma_gemm<1, false, true><<<pg, 256, 0, stream>>>(
            xzf, 256, 65536, Y1Th, Y1Tl, 256, 65536,
            nullptr, 256, 65536, Y2Th, Y2Tl, 256, 65536, 256, -1.f, 15.f);
        mfma_gemm<1, true, true><<<pg, 256, 0, stream>>>(
            zc, 256, 65536, Y2Th, Y2Tl, 256, 65536,
            xzf, 256, 65536, ZTh[1 - cur], ZTl[1 - cur], 256, 65536,
            256, -0.25f, 3.25f);
        cur = 1 - cur;
    }
    float* zfin = Zf[cur];

    // t2 = z @ (t1 / rs3); also emit t2^T split planes
    gemm_bk<false, true, true><<<dim3(1, 4, 32), 256, 0, stream>>>(
        zfin, 65536, 256, t1, 16384, 64, t2, 16384, 64, 256, rs3,
        t2Th, t2Tl);

    // F1: oh = softmax(q@kland^T)@t2 (in-place over q)
    attn1t2_mfma<<<dim3(64, 32), 256, 0, stream>>>(q, kland, t2Th, t2Tl, q);

    conv_add<<<32768, 256, 0, stream>>>(q, v, w_res);

    mfma_final<<<dim3(4, 128), 256, 0, stream>>>(q, WOTh, WOTl, out);

    (void)in_sizes; (void)n_in; (void)out_size; (void)ws_size;
}

// Round 5
// 1000.955 us; speedup vs baseline: 1.7574x; 1.1473x over previous
//
#include <hip/hip_runtime.h>

// ---------------------------------------------------------------------------
// Nystrom attention: split-bf16 (hi/lo, 3xMFMA) for ALL large GEMMs including
// flash attn kernels. fp32 only for tiny kernels + accumulators.
// R5: LDS-tiled depthwise conv (was 174us global-latency-bound, floor ~17us).
// B=4, N=4096, DIM=512, H=8, DH=64, M=256, l=16, 6 pinv iters, conv K=33.
// ---------------------------------------------------------------------------

typedef __attribute__((ext_vector_type(8))) short bf16x8;
typedef __attribute__((ext_vector_type(4))) float f32x4;

constexpr size_t SQ = 8388608;   // 32*4096*64
constexpr size_t SL = 524288;    // 32*256*64
constexpr size_t SA = 2097152;   // 32*256*256
constexpr size_t SP = 1048576;   // one bf16 plane of SA (float units)

constexpr size_t O_Q    = 0;                   // q -> later oh (in-place)
constexpr size_t O_K    = O_Q + SQ;            // k -> later zA,zB (f32)
constexpr size_t O_V    = O_K + SQ;
constexpr size_t O_QL   = O_V + SQ;
constexpr size_t O_KL   = O_QL + SL;
constexpr size_t O_A2   = O_KL + SL;
constexpr size_t O_T1   = O_A2 + SA;
constexpr size_t O_RS3  = O_T1 + SL;
constexpr size_t O_SCAL = O_RS3 + 8192;
constexpr size_t O_T2   = O_SCAL + 16;
constexpr size_t O_ZT0  = O_T2 + SL;
constexpr size_t O_ZT1  = O_ZT0 + 2 * SP;      // vT planes alias ZT1..Y2T (pre-pinv)
constexpr size_t O_XZT  = O_ZT1 + 2 * SP;      // t2T planes alias ZT1 (post-pinv)
constexpr size_t O_Y1T  = O_XZT + 2 * SP;
constexpr size_t O_Y2T  = O_Y1T + 2 * SP;
constexpr size_t O_WQT  = O_Y2T + 2 * SP;
constexpr size_t O_WOT  = O_WQT + 786432;
constexpr size_t O_END  = O_WOT + 262144;      // ~41M floats ~164 MB

// ---------------------------------------------------------------------------
__device__ __forceinline__ void split2(float x, unsigned short& h,
                                       unsigned short& l) {
    unsigned u  = __float_as_uint(x);
    unsigned hb = (u + 0x7FFFu + ((u >> 16) & 1u)) & 0xFFFF0000u;  // RNE hi
    h = (unsigned short)(hb >> 16);
    float d = x - __uint_as_float(hb);
    l = (unsigned short)(__float_as_uint(d) >> 16);
}

__device__ __forceinline__ f32x4 mfma3(bf16x8 ah, bf16x8 al, bf16x8 bh,
                                       bf16x8 bl, f32x4 c) {
    c = __builtin_amdgcn_mfma_f32_16x16x32_bf16(ah, bh, c, 0, 0, 0);
    c = __builtin_amdgcn_mfma_f32_16x16x32_bf16(ah, bl, c, 0, 0, 0);
    c = __builtin_amdgcn_mfma_f32_16x16x32_bf16(al, bh, c, 0, 0, 0);
    return c;
}

// split a float4 into hi/lo planes, write packed uint2 at H[off], L[off]
__device__ __forceinline__ void stage_split4(float4 av, unsigned short* H,
                                             unsigned short* L, int off) {
    unsigned short h0, h1, h2, h3, l0, l1, l2, l3;
    split2(av.x, h0, l0); split2(av.y, h1, l1);
    split2(av.z, h2, l2); split2(av.w, h3, l3);
    uint2 ph, pl;
    ph.x = (unsigned)h0 | ((unsigned)h1 << 16);
    ph.y = (unsigned)h2 | ((unsigned)h3 << 16);
    pl.x = (unsigned)l0 | ((unsigned)l1 << 16);
    pl.y = (unsigned)l2 | ((unsigned)l3 << 16);
    *(uint2*)&H[off] = ph;
    *(uint2*)&L[off] = pl;
}

// ---------------------------------------------------------------------------
// pinv-family MFMA GEMM, 64x128 tile: C = alpha*(A@B) + beta*A_elem.
// A fp32 (split in-register); B = transposed bf16 planes BT[n][k].
// grid (N/128=2, M/64=4, 32), block 256.
// ---------------------------------------------------------------------------
template <int EPI, bool WF32, bool WT>
__global__ __launch_bounds__(256) void mfma_gemm(
    const float* __restrict__ A, int lda, long saA,
    const unsigned short* __restrict__ BTh,
    const unsigned short* __restrict__ BTl, int ldbt, long sbT,
    float* __restrict__ C, int ldc, long scC,
    unsigned short* __restrict__ CTh, unsigned short* __restrict__ CTl,
    int ldct, long sct, int K, float alpha, float beta) {
    __shared__ unsigned short Ah[64 * 40], Al[64 * 40];
    __shared__ unsigned short Bh[128 * 40], Bl[128 * 40];
    const int t = threadIdx.x;
    const int wave = t >> 6, lane = t & 63, lm = lane & 15, lq = lane >> 4;
    const int z = blockIdx.z;
    const int m0 = blockIdx.y * 64, n0 = blockIdx.x * 128;
    const float* Ab = A + (size_t)z * saA;
    const unsigned short* BhB = BTh + (size_t)z * sbT;
    const unsigned short* BlB = BTl + (size_t)z * sbT;

    f32x4 acc[8];
#pragma unroll
    for (int j = 0; j < 8; ++j) acc[j] = (f32x4){0.f, 0.f, 0.f, 0.f};

    for (int kt = 0; kt < K; kt += 32) {
#pragma unroll
        for (int r = 0; r < 2; ++r) {
            int id = t + r * 256, row = id >> 3, k4 = (id & 7) * 4;
            float4 av = *(const float4*)(Ab + (size_t)(m0 + row) * lda + kt + k4);
            stage_split4(av, Ah, Al, row * 40 + k4);
        }
#pragma unroll
        for (int r = 0; r < 2; ++r) {
            int id = t + r * 256, row = id >> 2, ko = (id & 3) * 8;
            *(uint4*)&Bh[row * 40 + ko] =
                *(const uint4*)(BhB + (size_t)(n0 + row) * ldbt + kt + ko);
            *(uint4*)&Bl[row * 40 + ko] =
                *(const uint4*)(BlB + (size_t)(n0 + row) * ldbt + kt + ko);
        }
        __syncthreads();
        bf16x8 ah = *(const bf16x8*)&Ah[(wave * 16 + lm) * 40 + lq * 8];
        bf16x8 al = *(const bf16x8*)&Al[(wave * 16 + lm) * 40 + lq * 8];
#pragma unroll
        for (int j = 0; j < 8; ++j) {
            bf16x8 bh = *(const bf16x8*)&Bh[(j * 16 + lm) * 40 + lq * 8];
            bf16x8 bl = *(const bf16x8*)&Bl[(j * 16 + lm) * 40 + lq * 8];
            acc[j] = mfma3(ah, al, bh, bl, acc[j]);
        }
        __syncthreads();
    }

    float* Cb = C + (size_t)z * scC;
    unsigned short* CThB = CTh + (size_t)z * sct;
    unsigned short* CTlB = CTl + (size_t)z * sct;
    const int r0 = m0 + wave * 16 + lq * 4;
#pragma unroll
    for (int j = 0; j < 8; ++j) {
        int c = n0 + j * 16 + lm;
        float vals[4] = {acc[j][0], acc[j][1], acc[j][2], acc[j][3]};
        if (EPI == 1) {
#pragma unroll
            for (int e = 0; e < 4; ++e)
                vals[e] = alpha * vals[e] + beta * Ab[(size_t)(r0 + e) * lda + c];
        }
        if (WF32) {
#pragma unroll
            for (int e = 0; e < 4; ++e)
                Cb[(size_t)(r0 + e) * ldc + c] = vals[e];
        }
        if (WT) {
            unsigned short hh[4], ll[4];
#pragma unroll
            for (int e = 0; e < 4; ++e) split2(vals[e], hh[e], ll[e]);
            uint2 ph, pl;
            ph.x = (unsigned)hh[0] | ((unsigned)hh[1] << 16);
            ph.y = (unsigned)hh[2] | ((unsigned)hh[3] << 16);
            pl.x = (unsigned)ll[0] | ((unsigned)ll[1] << 16);
            pl.y = (unsigned)ll[2] | ((unsigned)ll[3] << 16);
            *(uint2*)&CThB[(size_t)c * ldct + r0] = ph;
            *(uint2*)&CTlB[(size_t)c * ldct + r0] = pl;
        }
    }
}

// ---------------------------------------------------------------------------
// qkv MFMA GEMM: x[16384,512] @ w_qkv planes; scatters q(*0.125)/k/v AND
// emits vT split-bf16 planes [bh][dh][4096].  grid (12, 128).
// ---------------------------------------------------------------------------
__global__ __launch_bounds__(256) void mfma_qkv(
    const float* __restrict__ X, const unsigned short* __restrict__ WTh,
    const unsigned short* __restrict__ WTl, float* __restrict__ qb,
    float* __restrict__ kb, float* __restrict__ vb,
    unsigned short* __restrict__ vTh, unsigned short* __restrict__ vTl) {
    __shared__ unsigned short Ah[128 * 40], Al[128 * 40];
    __shared__ unsigned short Bh[128 * 40], Bl[128 * 40];
    const int t = threadIdx.x;
    const int wave = t >> 6, lane = t & 63, lm = lane & 15, lq = lane >> 4;
    const int m0 = blockIdx.y * 128, n0 = blockIdx.x * 128;
    const int mb = (wave >> 1) * 64, nb = (wave & 1) * 64;
    f32x4 acc[4][4];
#pragma unroll
    for (int i = 0; i < 4; ++i)
#pragma unroll
        for (int j = 0; j < 4; ++j) acc[i][j] = (f32x4){0.f, 0.f, 0.f, 0.f};

    for (int kt = 0; kt < 512; kt += 32) {
#pragma unroll
        for (int r = 0; r < 4; ++r) {
            int id = t + r * 256, row = id >> 3, k4 = (id & 7) * 4;
            float4 av = *(const float4*)(X + (size_t)(m0 + row) * 512 + kt + k4);
            stage_split4(av, Ah, Al, row * 40 + k4);
        }
#pragma unroll
        for (int r = 0; r < 2; ++r) {
            int id = t + r * 256, row = id >> 2, ko = (id & 3) * 8;
            *(uint4*)&Bh[row * 40 + ko] =
                *(const uint4*)(WTh + (size_t)(n0 + row) * 512 + kt + ko);
            *(uint4*)&Bl[row * 40 + ko] =
                *(const uint4*)(WTl + (size_t)(n0 + row) * 512 + kt + ko);
        }
        __syncthreads();
        bf16x8 ah[4], al[4], bh[4], bl[4];
#pragma unroll
        for (int i = 0; i < 4; ++i) {
            ah[i] = *(const bf16x8*)&Ah[(mb + i * 16 + lm) * 40 + lq * 8];
            al[i] = *(const bf16x8*)&Al[(mb + i * 16 + lm) * 40 + lq * 8];
        }
#pragma unroll
        for (int j = 0; j < 4; ++j) {
            bh[j] = *(const bf16x8*)&Bh[(nb + j * 16 + lm) * 40 + lq * 8];
            bl[j] = *(const bf16x8*)&Bl[(nb + j * 16 + lm) * 40 + lq * 8];
        }
#pragma unroll
        for (int i = 0; i < 4; ++i)
#pragma unroll
            for (int j = 0; j < 4; ++j)
                acc[i][j] = mfma3(ah[i], al[i], bh[j], bl[j], acc[i][j]);
        __syncthreads();
    }
#pragma unroll
    for (int i = 0; i < 4; ++i)
#pragma unroll
        for (int j = 0; j < 4; ++j) {
            int r0 = m0 + mb + i * 16 + lq * 4;
            int c  = n0 + nb + j * 16 + lm;
            int which = c >> 9, h = (c >> 6) & 7, d = c & 63;
            float sc = (which == 0) ? 0.125f : 1.0f;
            float* dst = (which == 0) ? qb : (which == 1 ? kb : vb);
            int b = r0 >> 12, nbase = r0 & 4095;
#pragma unroll
            for (int e = 0; e < 4; ++e)
                dst[(size_t)(b * 8 + h) * 262144 + (size_t)(nbase + e) * 64 + d] =
                    acc[i][j][e] * sc;
            if (which == 2) {
                unsigned short hh[4], ll[4];
#pragma unroll
                for (int e = 0; e < 4; ++e) split2(acc[i][j][e], hh[e], ll[e]);
                uint2 ph, pl;
                ph.x = (unsigned)hh[0] | ((unsigned)hh[1] << 16);
                ph.y = (unsigned)hh[2] | ((unsigned)hh[3] << 16);
                pl.x = (unsigned)ll[0] | ((unsigned)ll[1] << 16);
                pl.y = (unsigned)ll[2] | ((unsigned)ll[3] << 16);
                size_t off = ((size_t)(b * 8 + h) * 64 + d) * 4096 + nbase;
                *(uint2*)&vTh[off] = ph;
                *(uint2*)&vTl[off] = pl;
            }
        }
}

// ---------------------------------------------------------------------------
// final MFMA GEMM: out[16384,512] = oh(gathered) @ w_out planes. grid (4,128)
// ---------------------------------------------------------------------------
__global__ __launch_bounds__(256) void mfma_final(
    const float* __restrict__ OH, const unsigned short* __restrict__ WTh,
    const unsigned short* __restrict__ WTl, float* __restrict__ out) {
    __shared__ unsigned short Ah[128 * 40], Al[128 * 40];
    __shared__ unsigned short Bh[128 * 40], Bl[128 * 40];
    const int t = threadIdx.x;
    const int wave = t >> 6, lane = t & 63, lm = lane & 15, lq = lane >> 4;
    const int m0 = blockIdx.y * 128, n0 = blockIdx.x * 128;
    const int mb = (wave >> 1) * 64, nb = (wave & 1) * 64;
    f32x4 acc[4][4];
#pragma unroll
    for (int i = 0; i < 4; ++i)
#pragma unroll
        for (int j = 0; j < 4; ++j) acc[i][j] = (f32x4){0.f, 0.f, 0.f, 0.f};

    for (int kt = 0; kt < 512; kt += 32) {
#pragma unroll
        for (int r = 0; r < 4; ++r) {
            int id = t + r * 256, row = id >> 3, k4g = kt + (id & 7) * 4;
            int gr = m0 + row, b = gr >> 12, n = gr & 4095;
            float4 av = *(const float4*)(OH + (size_t)(b * 8 + (k4g >> 6)) * 262144 +
                                         (size_t)n * 64 + (k4g & 63));
            stage_split4(av, Ah, Al, row * 40 + (id & 7) * 4);
        }
#pragma unroll
        for (int r = 0; r < 2; ++r) {
            int id = t + r * 256, row = id >> 2, ko = (id & 3) * 8;
            *(uint4*)&Bh[row * 40 + ko] =
                *(const uint4*)(WTh + (size_t)(n0 + row) * 512 + kt + ko);
            *(uint4*)&Bl[row * 40 + ko] =
                *(const uint4*)(WTl + (size_t)(n0 + row) * 512 + kt + ko);
        }
        __syncthreads();
        bf16x8 ah[4], al[4], bh[4], bl[4];
#pragma unroll
        for (int i = 0; i < 4; ++i) {
            ah[i] = *(const bf16x8*)&Ah[(mb + i * 16 + lm) * 40 + lq * 8];
            al[i] = *(const bf16x8*)&Al[(mb + i * 16 + lm) * 40 + lq * 8];
        }
#pragma unroll
        for (int j = 0; j < 4; ++j) {
            bh[j] = *(const bf16x8*)&Bh[(nb + j * 16 + lm) * 40 + lq * 8];
            bl[j] = *(const bf16x8*)&Bl[(nb + j * 16 + lm) * 40 + lq * 8];
        }
#pragma unroll
        for (int i = 0; i < 4; ++i)
#pragma unroll
            for (int j = 0; j < 4; ++j)
                acc[i][j] = mfma3(ah[i], al[i], bh[j], bl[j], acc[i][j]);
        __syncthreads();
    }
#pragma unroll
    for (int i = 0; i < 4; ++i)
#pragma unroll
        for (int j = 0; j < 4; ++j) {
            int r0 = m0 + mb + i * 16 + lq * 4;
            int c  = n0 + nb + j * 16 + lm;
#pragma unroll
            for (int e = 0; e < 4; ++e)
                out[(size_t)(r0 + e) * 512 + c] = acc[i][j][e];
        }
}

// ---------------------------------------------------------------------------
// F3 MFMA: t1 += exp(qland@k^T)@v, rs3 += rowsums. grid (8, 4, 32).
// ---------------------------------------------------------------------------
__global__ __launch_bounds__(256) void attn3v_mfma(
    const float* __restrict__ qland, const float* __restrict__ k,
    const unsigned short* __restrict__ vTh,
    const unsigned short* __restrict__ vTl,
    float* __restrict__ t1, float* __restrict__ rs3) {
    __shared__ unsigned short Qh[4608], Ql[4608];
    __shared__ unsigned short Kh[4608], Kl[4608];
    __shared__ unsigned short Eh[4608], El[4608];
    const int t = threadIdx.x;
    const int wave = t >> 6, lane = t & 63, lm = lane & 15, lq = lane >> 4;
    const int bz = blockIdx.z, m0 = blockIdx.y * 64, c0 = blockIdx.x * 8;
    const float* qb = qland + (size_t)bz * 16384;
    const float* kb = k + (size_t)bz * 262144;
    const unsigned short* vhb = vTh + (size_t)bz * 262144;
    const unsigned short* vlb = vTl + (size_t)bz * 262144;
#pragma unroll
    for (int r = 0; r < 4; ++r) {
        int id = t + r * 256, row = id >> 4, d4 = (id & 15) * 4;
        float4 av = *(const float4*)(qb + (size_t)(m0 + row) * 64 + d4);
        stage_split4(av, Qh, Ql, row * 72 + d4);
    }
    f32x4 acc[4];
#pragma unroll
    for (int j = 0; j < 4; ++j) acc[j] = (f32x4){0.f, 0.f, 0.f, 0.f};
    float rsum[4] = {0.f, 0.f, 0.f, 0.f};
    __syncthreads();

    for (int c = c0; c < c0 + 8; ++c) {
        const int tok0 = c * 64;
#pragma unroll
        for (int r = 0; r < 4; ++r) {
            int id = t + r * 256, row = id >> 4, d4 = (id & 15) * 4;
            float4 kv = *(const float4*)(kb + (size_t)(tok0 + row) * 64 + d4);
            stage_split4(kv, Kh, Kl, row * 72 + d4);
        }
        __syncthreads();
        bf16x8 a0  = *(const bf16x8*)&Qh[(wave * 16 + lm) * 72 + lq * 8];
        bf16x8 a0l = *(const bf16x8*)&Ql[(wave * 16 + lm) * 72 + lq * 8];
        bf16x8 a1  = *(const bf16x8*)&Qh[(wave * 16 + lm) * 72 + 32 + lq * 8];
        bf16x8 a1l = *(const bf16x8*)&Ql[(wave * 16 + lm) * 72 + 32 + lq * 8];
        f32x4 s[4];
#pragma unroll
        for (int j = 0; j < 4; ++j) s[j] = (f32x4){0.f, 0.f, 0.f, 0.f};
#pragma unroll
        for (int j = 0; j < 4; ++j) {
            bf16x8 b0  = *(const bf16x8*)&Kh[(j * 16 + lm) * 72 + lq * 8];
            bf16x8 b0l = *(const bf16x8*)&Kl[(j * 16 + lm) * 72 + lq * 8];
            bf16x8 b1  = *(const bf16x8*)&Kh[(j * 16 + lm) * 72 + 32 + lq * 8];
            bf16x8 b1l = *(const bf16x8*)&Kl[(j * 16 + lm) * 72 + 32 + lq * 8];
            s[j] = mfma3(a0, a0l, b0, b0l, s[j]);
            s[j] = mfma3(a1, a1l, b1, b1l, s[j]);
        }
        __syncthreads();
#pragma unroll
        for (int j = 0; j < 4; ++j)
#pragma unroll
            for (int e = 0; e < 4; ++e) {
                float ev = __expf(s[j][e]);
                rsum[e] += ev;
                unsigned short h, l;
                split2(ev, h, l);
                int off = (wave * 16 + lq * 4 + e) * 72 + j * 16 + lm;
                Eh[off] = h;
                El[off] = l;
            }
#pragma unroll
        for (int r = 0; r < 2; ++r) {
            int id = t + r * 256, dh = id >> 3, t8 = (id & 7) * 8;
            *(uint4*)&Kh[dh * 72 + t8] =
                *(const uint4*)(vhb + (size_t)dh * 4096 + tok0 + t8);
            *(uint4*)&Kl[dh * 72 + t8] =
                *(const uint4*)(vlb + (size_t)dh * 4096 + tok0 + t8);
        }
        __syncthreads();
        bf16x8 e0  = *(const bf16x8*)&Eh[(wave * 16 + lm) * 72 + lq * 8];
        bf16x8 e0l = *(const bf16x8*)&El[(wave * 16 + lm) * 72 + lq * 8];
        bf16x8 e1  = *(const bf16x8*)&Eh[(wave * 16 + lm) * 72 + 32 + lq * 8];
        bf16x8 e1l = *(const bf16x8*)&El[(wave * 16 + lm) * 72 + 32 + lq * 8];
#pragma unroll
        for (int j = 0; j < 4; ++j) {
            bf16x8 v0  = *(const bf16x8*)&Kh[(j * 16 + lm) * 72 + lq * 8];
            bf16x8 v0l = *(const bf16x8*)&Kl[(j * 16 + lm) * 72 + lq * 8];
            bf16x8 v1  = *(const bf16x8*)&Kh[(j * 16 + lm) * 72 + 32 + lq * 8];
            bf16x8 v1l = *(const bf16x8*)&Kl[(j * 16 + lm) * 72 + 32 + lq * 8];
            acc[j] = mfma3(e0, e0l, v0, v0l, acc[j]);
            acc[j] = mfma3(e1, e1l, v1, v1l, acc[j]);
        }
        __syncthreads();
    }
    float* t1b = t1 + (size_t)bz * 16384;
#pragma unroll
    for (int j = 0; j < 4; ++j)
#pragma unroll
        for (int e = 0; e < 4; ++e)
            atomicAdd(t1b + (size_t)(m0 + wave * 16 + lq * 4 + e) * 64 +
                          j * 16 + lm,
                      acc[j][e]);
#pragma unroll
    for (int e = 0; e < 4; ++e) {
        float vs = rsum[e];
        for (int mm = 1; mm < 16; mm <<= 1) vs += __shfl_xor(vs, mm);
        if (lm == 0)
            atomicAdd(rs3 + bz * 256 + m0 + wave * 16 + lq * 4 + e, vs);
    }
}

// ---------------------------------------------------------------------------
// F1 MFMA: oh = softmax(q@kland^T) @ t2 (normalized), in-place over q.
// grid (64, 32).
// ---------------------------------------------------------------------------
__global__ __launch_bounds__(256) void attn1t2_mfma(
    const float* __restrict__ q, const float* __restrict__ kland,
    const unsigned short* __restrict__ t2Th,
    const unsigned short* __restrict__ t2Tl, float* __restrict__ oh) {
    __shared__ unsigned short Qh[4608], Ql[4608];
    __shared__ unsigned short Kh[4608], Kl[4608];
    __shared__ unsigned short Eh[4608], El[4608];
    const int t = threadIdx.x;
    const int wave = t >> 6, lane = t & 63, lm = lane & 15, lq = lane >> 4;
    const int bz = blockIdx.y, m0 = blockIdx.x * 64;
    const float* qb  = q + (size_t)bz * 262144;
    const float* klb = kland + (size_t)bz * 16384;
    const unsigned short* t2h = t2Th + (size_t)bz * 16384;
    const unsigned short* t2l = t2Tl + (size_t)bz * 16384;
#pragma unroll
    for (int r = 0; r < 4; ++r) {
        int id = t + r * 256, row = id >> 4, d4 = (id & 15) * 4;
        float4 av = *(const float4*)(qb + (size_t)(m0 + row) * 64 + d4);
        stage_split4(av, Qh, Ql, row * 72 + d4);
    }
    f32x4 acc[4];
#pragma unroll
    for (int j = 0; j < 4; ++j) acc[j] = (f32x4){0.f, 0.f, 0.f, 0.f};
    float rsum[4] = {0.f, 0.f, 0.f, 0.f};
    __syncthreads();

    for (int lc = 0; lc < 4; ++lc) {
        const int l0 = lc * 64;
#pragma unroll
        for (int r = 0; r < 4; ++r) {
            int id = t + r * 256, row = id >> 4, d4 = (id & 15) * 4;
            float4 kv = *(const float4*)(klb + (size_t)(l0 + row) * 64 + d4);
            stage_split4(kv, Kh, Kl, row * 72 + d4);
        }
        __syncthreads();
        bf16x8 a0  = *(const bf16x8*)&Qh[(wave * 16 + lm) * 72 + lq * 8];
        bf16x8 a0l = *(const bf16x8*)&Ql[(wave * 16 + lm) * 72 + lq * 8];
        bf16x8 a1  = *(const bf16x8*)&Qh[(wave * 16 + lm) * 72 + 32 + lq * 8];
        bf16x8 a1l = *(const bf16x8*)&Ql[(wave * 16 + lm) * 72 + 32 + lq * 8];
        f32x4 s[4];
#pragma unroll
        for (int j = 0; j < 4; ++j) s[j] = (f32x4){0.f, 0.f, 0.f, 0.f};
#pragma unroll
        for (int j = 0; j < 4; ++j) {
            bf16x8 b0  = *(const bf16x8*)&Kh[(j * 16 + lm) * 72 + lq * 8];
            bf16x8 b0l = *(const bf16x8*)&Kl[(j * 16 + lm) * 72 + lq * 8];
            bf16x8 b1  = *(const bf16x8*)&Kh[(j * 16 + lm) * 72 + 32 + lq * 8];
            bf16x8 b1l = *(const bf16x8*)&Kl[(j * 16 + lm) * 72 + 32 + lq * 8];
            s[j] = mfma3(a0, a0l, b0, b0l, s[j]);
            s[j] = mfma3(a1, a1l, b1, b1l, s[j]);
        }
        __syncthreads();
#pragma unroll
        for (int j = 0; j < 4; ++j)
#pragma unroll
            for (int e = 0; e < 4; ++e) {
                float ev = __expf(s[j][e]);
                rsum[e] += ev;
                unsigned short h, l;
                split2(ev, h, l);
                int off = (wave * 16 + lq * 4 + e) * 72 + j * 16 + lm;
                Eh[off] = h;
                El[off] = l;
            }
#pragma unroll
        for (int r = 0; r < 2; ++r) {
            int id = t + r * 256, dh = id >> 3, t8 = (id & 7) * 8;
            *(uint4*)&Kh[dh * 72 + t8] =
                *(const uint4*)(t2h + (size_t)dh * 256 + l0 + t8);
            *(uint4*)&Kl[dh * 72 + t8] =
                *(const uint4*)(t2l + (size_t)dh * 256 + l0 + t8);
        }
        __syncthreads();
        bf16x8 e0  = *(const bf16x8*)&Eh[(wave * 16 + lm) * 72 + lq * 8];
        bf16x8 e0l = *(const bf16x8*)&El[(wave * 16 + lm) * 72 + lq * 8];
        bf16x8 e1  = *(const bf16x8*)&Eh[(wave * 16 + lm) * 72 + 32 + lq * 8];
        bf16x8 e1l = *(const bf16x8*)&El[(wave * 16 + lm) * 72 + 32 + lq * 8];
#pragma unroll
        for (int j = 0; j < 4; ++j) {
            bf16x8 v0  = *(const bf16x8*)&Kh[(j * 16 + lm) * 72 + lq * 8];
            bf16x8 v0l = *(const bf16x8*)&Kl[(j * 16 + lm) * 72 + lq * 8];
            bf16x8 v1  = *(const bf16x8*)&Kh[(j * 16 + lm) * 72 + 32 + lq * 8];
            bf16x8 v1l = *(const bf16x8*)&Kl[(j * 16 + lm) * 72 + 32 + lq * 8];
            acc[j] = mfma3(e0, e0l, v0, v0l, acc[j]);
            acc[j] = mfma3(e1, e1l, v1, v1l, acc[j]);
        }
        __syncthreads();
    }
    float rinv[4];
#pragma unroll
    for (int e = 0; e < 4; ++e) {
        float vs = rsum[e];
        for (int mm = 1; mm < 16; mm <<= 1) vs += __shfl_xor(vs, mm);
        rinv[e] = 1.0f / vs;
    }
    float* ohb = oh + (size_t)bz * 262144;
#pragma unroll
    for (int j = 0; j < 4; ++j)
#pragma unroll
        for (int e = 0; e < 4; ++e)
            ohb[(size_t)(m0 + wave * 16 + lq * 4 + e) * 64 + j * 16 + lm] =
                acc[j][e] * rinv[e];
}

// ---------------------------------------------------------------------------
// weight transpose+split: W[512][N] -> planes T[N][512]
// ---------------------------------------------------------------------------
__global__ void wtrans(const float* __restrict__ W, int N,
                       unsigned short* __restrict__ Th,
                       unsigned short* __restrict__ Tl) {
    int idx = blockIdx.x * 256 + threadIdx.x;
    int n = idx >> 9, kk = idx & 511;
    float x = W[(size_t)kk * N + n];
    unsigned short h, l;
    split2(x, h, l);
    Th[idx] = h;
    Tl[idx] = l;
}

// ---------------------------------------------------------------------------
// fp32 64x64 micro-kernel + gemm_bk (attn2 + t2 only)
// ---------------------------------------------------------------------------
__device__ __forceinline__ void mt16(const float* As, const float* Bs,
                                     int ty4, int tx4, float (&acc)[4][4]) {
#pragma unroll
    for (int kk = 0; kk < 16; ++kk) {
        float4 a4 = *(const float4*)(As + kk * 68 + ty4);
        float4 b4 = *(const float4*)(Bs + kk * 68 + tx4);
        float aa[4] = {a4.x, a4.y, a4.z, a4.w};
        float bb[4] = {b4.x, b4.y, b4.z, b4.w};
#pragma unroll
        for (int u = 0; u < 4; ++u)
#pragma unroll
            for (int w = 0; w < 4; ++w)
                acc[u][w] += aa[u] * bb[w];
    }
}

template <bool TRANSB, bool DIVB, bool WTOUT>
__global__ __launch_bounds__(256) void gemm_bk(
    const float* __restrict__ A, int saA, int lda,
    const float* __restrict__ B, int sbB, int ldb,
    float* __restrict__ C, int scC, int ldc,
    int K, const float* __restrict__ divv,
    unsigned short* __restrict__ CTh, unsigned short* __restrict__ CTl) {
    __shared__ float As[16 * 68];
    __shared__ float Bs[16 * 68];
    const int t  = threadIdx.x;
    const int z  = blockIdx.z;
    const int m0 = blockIdx.y * 64;
    const int n0 = blockIdx.x * 64;
    const float* Ab = A + (size_t)z * saA;
    const float* Bb = B + (size_t)z * sbB;
    float*       Cb = C + (size_t)z * scC;
    const int tx4 = (t & 15) * 4;
    const int ty4 = (t >> 4) * 4;
    const int ar  = t >> 2, ak = (t & 3) * 4;
    const int bkr = t >> 4, bc4 = (t & 15) * 4;
    float acc[4][4] = {};
    for (int kt = 0; kt < K; kt += 16) {
        float4 av = *(const float4*)(Ab + (size_t)(m0 + ar) * lda + kt + ak);
        float4 bv;
        if (TRANSB) {
            bv = *(const float4*)(Bb + (size_t)(n0 + ar) * ldb + kt + ak);
        } else {
            bv = *(const float4*)(Bb + (size_t)(kt + bkr) * ldb + n0 + bc4);
            if (DIVB) {
                float r = 1.0f / divv[z * K + kt + bkr];
                bv.x *= r; bv.y *= r; bv.z *= r; bv.w *= r;
            }
        }
        As[(ak + 0) * 68 + ar] = av.x;
        As[(ak + 1) * 68 + ar] = av.y;
        As[(ak + 2) * 68 + ar] = av.z;
        As[(ak + 3) * 68 + ar] = av.w;
        if (TRANSB) {
            Bs[(ak + 0) * 68 + ar] = bv.x;
            Bs[(ak + 1) * 68 + ar] = bv.y;
            Bs[(ak + 2) * 68 + ar] = bv.z;
            Bs[(ak + 3) * 68 + ar] = bv.w;
        } else {
            *(float4*)(Bs + bkr * 68 + bc4) = bv;
        }
        __syncthreads();
        mt16(As, Bs, ty4, tx4, acc);
        __syncthreads();
    }
#pragma unroll
    for (int u = 0; u < 4; ++u) {
        int row = m0 + ty4 + u;
        *(float4*)(Cb + (size_t)row * ldc + n0 + tx4) =
            make_float4(acc[u][0], acc[u][1], acc[u][2], acc[u][3]);
    }
    if (WTOUT) {
#pragma unroll
        for (int w = 0; w < 4; ++w) {
            unsigned short hh[4], ll[4];
#pragma unroll
            for (int u = 0; u < 4; ++u) split2(acc[u][w], hh[u], ll[u]);
            uint2 ph, pl;
            ph.x = (unsigned)hh[0] | ((unsigned)hh[1] << 16);
            ph.y = (unsigned)hh[2] | ((unsigned)hh[3] << 16);
            pl.x = (unsigned)ll[0] | ((unsigned)ll[1] << 16);
            pl.y = (unsigned)ll[2] | ((unsigned)ll[3] << 16);
            size_t off = (size_t)z * 16384 + (size_t)(n0 + tx4 + w) * 256 +
                         m0 + ty4;
            *(uint2*)&CTh[off] = ph;
            *(uint2*)&CTl[off] = pl;
        }
    }
}

// ---------------------------------------------------------------------------
// small kernels
// ---------------------------------------------------------------------------
__global__ void zero_f(float* __restrict__ p, int n) {
    int i = blockIdx.x * 256 + threadIdx.x;
    if (i < n) p[i] = 0.f;
}

__global__ void landmark_mean(const float* __restrict__ src,
                              float* __restrict__ dst) {
    int o = blockIdx.x * 256 + threadIdx.x;
    int d = o & 63, m = (o >> 6) & 255, bh = o >> 14;
    const float* s = src + (size_t)bh * 262144 + (size_t)m * 1024 + d;
    float acc = 0.f;
#pragma unroll
    for (int j = 0; j < 16; ++j) acc += s[j * 64];
    dst[o] = acc * (1.0f / 16.0f);
}

__global__ void softmax_rows(float* __restrict__ a) {
    __shared__ float red[256];
    int row = blockIdx.x, t = threadIdx.x;
    float v = a[(size_t)row * 256 + t];
    red[t] = v;
    __syncthreads();
    for (int s = 128; s > 0; s >>= 1) {
        if (t < s) red[t] = fmaxf(red[t], red[t + s]);
        __syncthreads();
    }
    float mx = red[0];
    __syncthreads();
    float e = __expf(v - mx);
    red[t] = e;
    __syncthreads();
    for (int s = 128; s > 0; s >>= 1) {
        if (t < s) red[t] += red[t + s];
        __syncthreads();
    }
    a[(size_t)row * 256 + t] = e / red[0];
}

__global__ __launch_bounds__(256) void scalar_prep(const float* __restrict__ a,
                                                   float* __restrict__ scal) {
    __shared__ float red[256];
    int bh = blockIdx.x, t = threadIdx.x;
    const float* ab = a + (size_t)bh * 65536;
    float cs = 0.f;
    for (int i = 0; i < 256; ++i) cs += ab[i * 256 + t];
    red[t] = cs;
    __syncthreads();
    for (int s = 128; s > 0; s >>= 1) {
        if (t < s) red[t] = fmaxf(red[t], red[t + s]);
        __syncthreads();
    }
    float mcol = red[0];
    __syncthreads();
    float rs = 0.f;
    for (int j = 0; j < 256; ++j) rs += ab[t * 256 + j];
    red[t] = rs;
    __syncthreads();
    for (int s = 128; s > 0; s >>= 1) {
        if (t < s) red[t] = fmaxf(red[t], red[t + s]);
        __syncthreads();
    }
    if (t == 0) {
        atomicMax((unsigned int*)&scal[0], __float_as_uint(mcol));
        atomicMax((unsigned int*)&scal[1], __float_as_uint(red[0]));
    }
}

__global__ void zinit(const float* __restrict__ a, float* __restrict__ zz,
                      unsigned short* __restrict__ zTh,
                      unsigned short* __restrict__ zTl,
                      const float* __restrict__ scal) {
    int idx = blockIdx.x * 256 + threadIdx.x;
    int bh = idx >> 16, r = (idx >> 8) & 255, c = idx & 255;
    float denom = scal[0] * scal[1] + 1e-8f;
    float v = a[idx] / denom;
    zz[((size_t)bh << 16) + ((size_t)c << 8) + r] = v;
    unsigned short h, l;
    split2(v, h, l);
    zTh[idx] = h;
    zTl[idx] = l;
}

// ---------------------------------------------------------------------------
// LDS-tiled depthwise conv: oh += conv33(v).  grid (32 tiles, 32 bh).
// Each block: 128 tokens x 64 dh; v window staged once in LDS (zero-padded).
// Sliding 33-tap register window -> ~2 LDS reads per output.
// ---------------------------------------------------------------------------
__global__ __launch_bounds__(256) void conv_tiled(
    float* __restrict__ oh, const float* __restrict__ v,
    const float* __restrict__ wres) {
    __shared__ float Vs[160 * 64];
    __shared__ float Ws[33];
    const int t = threadIdx.x;
    const int bh = blockIdx.y;
    const int n0 = blockIdx.x * 128;
    const int h = bh & 7;
    const float* vb = v + (size_t)bh * 262144;
    if (t < 33) Ws[t] = wres[h * 33 + t];
#pragma unroll
    for (int r = 0; r < 10; ++r) {
        int id = t + r * 256;               // 2560 float4 = 160 rows x 16
        int row = id >> 4, d4 = (id & 15) * 4;
        int n = n0 - 16 + row;
        float4 val = make_float4(0.f, 0.f, 0.f, 0.f);
        if ((unsigned)n < 4096u)
            val = *(const float4*)(vb + (size_t)n * 64 + d4);
        *(float4*)&Vs[row * 64 + d4] = val;
    }
    __syncthreads();
    // thread -> d = t&63, token group base = (t>>6)*32 (4 groups of 32)
    const int d = t & 63;
    const int g0 = (t >> 6) * 32;
    float* ohb = oh + (size_t)bh * 262144 + (size_t)n0 * 64;
    float w[33];
#pragma unroll
    for (int j = 0; j < 33; ++j) w[j] = Vs[(g0 + j) * 64 + d];
#pragma unroll
    for (int i = 0; i < 32; ++i) {
        float acc = ohb[(size_t)(g0 + i) * 64 + d];
#pragma unroll
        for (int tt = 0; tt < 33; ++tt) acc += w[tt] * Ws[tt];
        ohb[(size_t)(g0 + i) * 64 + d] = acc;
        // shift window, load next
        if (i < 31) {
#pragma unroll
            for (int j = 0; j < 32; ++j) w[j] = w[j + 1];
            w[32] = Vs[(g0 + i + 33) * 64 + d];
        }
    }
}

// ---------------------------------------------------------------------------
extern "C" void kernel_launch(void* const* d_in, const int* in_sizes, int n_in,
                              void* d_out, int out_size, void* d_ws, size_t ws_size,
                              hipStream_t stream) {
    const float* x     = (const float*)d_in[0];
    const float* w_qkv = (const float*)d_in[1];
    const float* w_out = (const float*)d_in[2];
    const float* w_res = (const float*)d_in[3];
    float* out = (float*)d_out;
    float* ws  = (float*)d_ws;

    float* q     = ws + O_Q;
    float* k     = ws + O_K;
    float* v     = ws + O_V;
    float* qland = ws + O_QL;
    float* kland = ws + O_KL;
    float* attn2 = ws + O_A2;
    float* t1    = ws + O_T1;
    float* rs3   = ws + O_RS3;
    float* scal  = ws + O_SCAL;
    float* t2    = ws + O_T2;
    float* zA    = k;
    float* zB    = k + SA;

    unsigned short* ZT0h = (unsigned short*)(ws + O_ZT0);
    unsigned short* ZT0l = (unsigned short*)(ws + O_ZT0 + SP);
    unsigned short* ZT1h = (unsigned short*)(ws + O_ZT1);
    unsigned short* ZT1l = (unsigned short*)(ws + O_ZT1 + SP);
    unsigned short* XZTh = (unsigned short*)(ws + O_XZT);
    unsigned short* XZTl = (unsigned short*)(ws + O_XZT + SP);
    unsigned short* Y1Th = (unsigned short*)(ws + O_Y1T);
    unsigned short* Y1Tl = (unsigned short*)(ws + O_Y1T + SP);
    unsigned short* Y2Th = (unsigned short*)(ws + O_Y2T);
    unsigned short* Y2Tl = (unsigned short*)(ws + O_Y2T + SP);
    unsigned short* WQTh = (unsigned short*)(ws + O_WQT);
    unsigned short* WQTl = (unsigned short*)(ws + O_WQT + 393216);
    unsigned short* WOTh = (unsigned short*)(ws + O_WOT);
    unsigned short* WOTl = (unsigned short*)(ws + O_WOT + 131072);
    unsigned short* vTh = (unsigned short*)(ws + O_ZT1);
    unsigned short* vTl = vTh + 8388608;
    unsigned short* t2Th = (unsigned short*)(ws + O_ZT1);
    unsigned short* t2Tl = t2Th + 524288;

    zero_f<<<2081, 256, 0, stream>>>(t1, 532496);   // t1+rs3+scal
    wtrans<<<3072, 256, 0, stream>>>(w_qkv, 1536, WQTh, WQTl);
    wtrans<<<1024, 256, 0, stream>>>(w_out, 512, WOTh, WOTl);

    mfma_qkv<<<dim3(12, 128), 256, 0, stream>>>(x, WQTh, WQTl, q, k, v,
                                                vTh, vTl);

    landmark_mean<<<2048, 256, 0, stream>>>(q, qland);
    landmark_mean<<<2048, 256, 0, stream>>>(k, kland);

    gemm_bk<true, false, false><<<dim3(4, 4, 32), 256, 0, stream>>>(
        qland, 16384, 64, kland, 16384, 64, attn2, 65536, 256, 64, nullptr,
        nullptr, nullptr);
    softmax_rows<<<8192, 256, 0, stream>>>(attn2);
    scalar_prep<<<32, 256, 0, stream>>>(attn2, scal);

    // F3 before pinv (k and vT planes die here)
    attn3v_mfma<<<dim3(8, 4, 32), 256, 0, stream>>>(qland, k, vTh, vTl, t1, rs3);

    zinit<<<8192, 256, 0, stream>>>(attn2, zA, ZT0h, ZT0l, scal);

    unsigned short* ZTh[2] = {ZT0h, ZT1h};
    unsigned short* ZTl[2] = {ZT0l, ZT1l};
    float* Zf[2] = {zA, zB};
    int cur = 0;
    const dim3 pg(2, 4, 32);
    for (int it = 0; it < 6; ++it) {
        float* zc  = Zf[cur];
        float* xzf = Zf[1 - cur];
        mfma_gemm<0, true, true><<<pg, 256, 0, stream>>>(
            attn2, 256, 65536, ZTh[cur], ZTl[cur], 256, 65536,
            xzf, 256, 65536, XZTh, XZTl, 256, 65536, 256, 0.f, 0.f);
        mfma_gemm<1, false, true><<<pg, 256, 0, stream>>>(
            xzf, 256, 65536, XZTh, XZTl, 256, 65536,
            nullptr, 256, 65536, Y1Th, Y1Tl, 256, 65536, 256, -1.f, 7.f);
        mfma_gemm<1, false, true><<<pg, 256, 0, stream>>>(
            xzf, 256, 65536, Y1Th, Y1Tl, 256, 65536,
            nullptr, 256, 65536, Y2Th, Y2Tl, 256, 65536, 256, -1.f, 15.f);
        mfma_gemm<1, true, true><<<pg, 256, 0, stream>>>(
            zc, 256, 65536, Y2Th, Y2Tl, 256, 65536,
            xzf, 256, 65536, ZTh[1 - cur], ZTl[1 - cur], 256, 65536,
            256, -0.25f, 3.25f);
        cur = 1 - cur;
    }
    float* zfin = Zf[cur];

    // t2 = z @ (t1 / rs3); also emit t2^T split planes
    gemm_bk<false, true, true><<<dim3(1, 4, 32), 256, 0, stream>>>(
        zfin, 65536, 256, t1, 16384, 64, t2, 16384, 64, 256, rs3,
        t2Th, t2Tl);

    // F1: oh = softmax(q@kland^T)@t2 (in-place over q)
    attn1t2_mfma<<<dim3(64, 32), 256, 0, stream>>>(q, kland, t2Th, t2Tl, q);

    // oh += depthwise conv(v), LDS-tiled
    conv_tiled<<<dim3(32, 32), 256, 0, stream>>>(q, v, w_res);

    mfma_final<<<dim3(4, 128), 256, 0, stream>>>(q, WOTh, WOTl, out);

    (void)in_sizes; (void)n_in; (void)out_size; (void)ws_size;
}